// Round 16
// baseline (188.416 us; speedup 1.0000x reference)
//
#include <hip/hip_runtime.h>
#include <math.h>

// Problem constants (match reference)
constexpr int kS  = 256;
constexpr int kB  = 16;
constexpr int kL  = 36;
constexpr int kN  = 400000;
constexpr int kNA = 50000;
constexpr int kNB = 50000;
constexpr int kNC = 50000;

constexpr int kImgElems = kB * kS * kS;  // 1,048,576
constexpr int kNStrip = 32;              // strips per image (8 rows each)
constexpr int kStripRows = 8;
constexpr int kCAP = 16384;              // records per bucket (expected ~13K)
constexpr float kFxScale = 1048576.f;    // 2^20 fixed-point scale for deposit
constexpr int kProjStride = 80;          // floats per b in proj table
constexpr int kPB = 256;                 // threads (points) per project block
constexpr int kProjBlocks = (kN + kPB - 1) / kPB;   // 1563
constexpr int kAtomBlocks = (kNA + kPB - 1) / kPB;  // 196
constexpr int kNCnt = kB * kNStrip;      // 512 bucket counters

// ---------------------------------------------------------------------------
// ctf transpose (+ fused prep in block 0): ctfT[b][x][y] = ctf[b][y][x]
// ---------------------------------------------------------------------------
__global__ __launch_bounds__(256) void k_ctfT(
    const float* __restrict__ ctf, float* __restrict__ ctfT,
    const float* __restrict__ zx, const float* __restrict__ zy,
    const float* __restrict__ zz, const float* __restrict__ de,
    const float* __restrict__ dsh, float* __restrict__ proj) {
  __shared__ float tile[32][33];
  int b = blockIdx.z;
  int x0 = blockIdx.x * 32, y0 = blockIdx.y * 32;
  int tx = threadIdx.x & 31, ty4 = threadIdx.x >> 5;  // 32 x 8
  const float* src = ctf + (size_t)b * kS * kS;
  float* dst = ctfT + (size_t)b * kS * kS;
#pragma unroll
  for (int r = 0; r < 4; ++r) {
    int y = y0 + ty4 + r * 8;
    tile[ty4 + r * 8][tx] = src[y * kS + x0 + tx];
  }
  __syncthreads();
#pragma unroll
  for (int r = 0; r < 4; ++r) {
    int x = x0 + ty4 + r * 8;
    dst[(size_t)x * kS + y0 + tx] = tile[tx][ty4 + r * 8];
  }
  // fused prep: per-b combined projection weights (block 0 only)
  if (b == 0 && blockIdx.x == 0 && blockIdx.y == 0 && threadIdx.x < kB) {
    int pbi = threadIdx.x;
    float a = de[pbi * 3 + 0], bb = de[pbi * 3 + 1], g = de[pbi * 3 + 2];
    float ca, sa, cb, sb, cg, sg;
    sincosf(a, &sa, &ca);
    sincosf(bb, &sb, &cb);
    sincosf(g, &sg, &cg);
    float R0 = cg * cb * ca - sg * sa;
    float R1 = cg * cb * sa + sg * ca;
    float R2 = -cg * sb;
    float R3 = -sg * cb * ca - cg * sa;
    float R4 = -sg * cb * sa + cg * ca;
    float R5 = sg * sb;
    float* p = proj + pbi * kProjStride;
    for (int l = 0; l < kL; ++l) {
      float x = zx[pbi * kL + l], y = zy[pbi * kL + l], z = zz[pbi * kL + l];
      p[l]      = R0 * x + R1 * y + R2 * z;
      p[kL + l] = R3 * x + R4 * y + R5 * z;
    }
    p[72] = R0; p[73] = R1; p[74] = R2;
    p[75] = R3; p[76] = R4; p[77] = R5;
    p[78] = dsh[pbi * 2 + 0] + 128.0f;
    p[79] = dsh[pbi * 2 + 1] + 128.0f;
  }
}

// ---------------------------------------------------------------------------
// Phase 1: project (+ fused atoms in trailing blocks). ROUND-11 VERIFIED FORM
// with 32 strips of 8 rows (512 buckets). 256 thr/block, 1 point/thread,
// all 16 b's, VGPR ~64.
// Record (8B): x0+1:9 | y0+1:9 | qwx:11 | qwy:11 | qv:24
// ---------------------------------------------------------------------------
__global__ __launch_bounds__(kPB, 2) void k_project(
    const float* __restrict__ proj, const float* __restrict__ Zvol,
    const float* __restrict__ coords, const float* __restrict__ values,
    uint2* __restrict__ arena, unsigned* __restrict__ gcnt,
    const float* __restrict__ zx, const float* __restrict__ zy,
    const float* __restrict__ zz, const float* __restrict__ Za,
    const float* __restrict__ ac, float* __restrict__ atoms) {
  int tid = threadIdx.x;

  if (blockIdx.x >= kProjBlocks) {
    // ------------------ fused k_atoms path ------------------
    int i = (blockIdx.x - kProjBlocks) * kPB + tid;
    if (i >= kNA) return;
    float Zv[kL];
    const float4* zrow = reinterpret_cast<const float4*>(Za + (size_t)i * kL);
#pragma unroll
    for (int q = 0; q < kL / 4; ++q) {
      float4 f = zrow[q];
      Zv[4 * q + 0] = f.x; Zv[4 * q + 1] = f.y;
      Zv[4 * q + 2] = f.z; Zv[4 * q + 3] = f.w;
    }
    float ax = ac[(size_t)i * 3 + 0];
    float ay = ac[(size_t)i * 3 + 1];
    float az = ac[(size_t)i * 3 + 2];
    for (int b = 0; b < kB; ++b) {
      float dx = 0.f, dy = 0.f, dz = 0.f;
#pragma unroll
      for (int l = 0; l < kL; ++l) {
        float zvl = Zv[l];
        dx = fmaf(zx[b * kL + l], zvl, dx);
        dy = fmaf(zy[b * kL + l], zvl, dy);
        dz = fmaf(zz[b * kL + l], zvl, dz);
      }
      size_t o = ((size_t)b * kNA + i) * 3;
      atoms[o + 0] = ax + dx;
      atoms[o + 1] = ay + dy;
      atoms[o + 2] = az + dz;
    }
    return;
  }

  // ------------------ project path ------------------
  __shared__ unsigned s_cnt[kNCnt];   // 512 counters
  __shared__ unsigned s_base[kNCnt];
  s_cnt[tid] = 0u;
  s_cnt[tid + kPB] = 0u;

  int n = blockIdx.x * kPB + tid;
  bool act = n < kN;
  float Zv[kL];
  float cx0 = 0.f, cy0 = 0.f, cz0 = 0.f, v = 0.f;
  if (act) {
    const float4* zrow = reinterpret_cast<const float4*>(Zvol + (size_t)n * kL);
#pragma unroll
    for (int q = 0; q < kL / 4; ++q) {
      float4 f = zrow[q];
      Zv[4 * q + 0] = f.x; Zv[4 * q + 1] = f.y;
      Zv[4 * q + 2] = f.z; Zv[4 * q + 3] = f.w;
    }
    cx0 = coords[(size_t)n * 3 + 0];
    cy0 = coords[(size_t)n * 3 + 1];
    cz0 = coords[(size_t)n * 3 + 2];
    v = values[n];
  }
  unsigned qv = (unsigned)(v * 16777216.f);
  if (qv > 16777215u) qv = 16777215u;
  __syncthreads();  // counters zeroed

  int fxq[kB], fyq[kB];
  unsigned flags = 0;

  // pass 1: compute + count
#pragma unroll
  for (int b = 0; b < kB; ++b) {
    const float* pb = proj + b * kProjStride;  // uniform -> s_loads
    float fx = pb[72] * cx0 + pb[73] * cy0 + pb[74] * cz0 + pb[78];
    float fy = pb[75] * cx0 + pb[76] * cy0 + pb[77] * cz0 + pb[79];
#pragma unroll
    for (int l = 0; l < kL; ++l) {
      float zvl = Zv[l];
      fx = fmaf(pb[l], zvl, fx);
      fy = fmaf(pb[kL + l], zvl, fy);
    }
    int xq = (int)floorf(fx * 2048.f);
    int yq = (int)floorf(fy * 2048.f);
    fxq[b] = xq;
    fyq[b] = yq;
    int x0 = xq >> 11, y0 = yq >> 11;
    if (act && x0 >= -1 && x0 <= 255 && y0 >= -1 && y0 <= 255) {
      flags |= 1u << b;
      int q0 = y0 >> 3;        // may be -1 (y0 = -1 -> -1)
      int q1 = (y0 + 1) >> 3;  // 0..32
      if (q0 >= 0) atomicAdd(&s_cnt[b * kNStrip + q0], 1u);
      if (q1 <= 31 && q1 != q0) atomicAdd(&s_cnt[b * kNStrip + q1], 1u);
    }
  }
  __syncthreads();

  // reserve: one concurrent global atomic round, 2 counters per thread
#pragma unroll
  for (int c0 = 0; c0 < kNCnt; c0 += kPB) {
    int c = c0 + tid;
    unsigned cnt = s_cnt[c];
    s_base[c] = cnt ? atomicAdd(&gcnt[c], cnt) : 0u;
    s_cnt[c] = 0u;  // reset for slot pass
  }
  __syncthreads();

  // pass 2: slots + writes (no trailing barrier; stores drain at kernel end)
#pragma unroll
  for (int b = 0; b < kB; ++b) {
    if (!((flags >> b) & 1u)) continue;
    int xq = fxq[b], yq = fyq[b];
    int x0 = xq >> 11, y0 = yq >> 11;
    unsigned qwx = (unsigned)(xq & 2047), qwy = (unsigned)(yq & 2047);
    uint2 rec;
    rec.x = (unsigned)(x0 + 1) | ((unsigned)(y0 + 1) << 9) | (qwx << 18) |
            ((qwy & 7u) << 29);
    rec.y = (qwy >> 3) | (qv << 8);
    int q0 = y0 >> 3;
    int q1 = (y0 + 1) >> 3;
    if (q0 >= 0) {
      int c = b * kNStrip + q0;
      unsigned sl = atomicAdd(&s_cnt[c], 1u);
      unsigned idx = s_base[c] + sl;
      if (idx < (unsigned)kCAP) arena[(size_t)c * kCAP + idx] = rec;
    }
    if (q1 <= 31 && q1 != q0) {
      int c = b * kNStrip + q1;
      unsigned sl = atomicAdd(&s_cnt[c], 1u);
      unsigned idx = s_base[c] + sl;
      if (idx < (unsigned)kCAP) arena[(size_t)c * kCAP + idx] = rec;
    }
  }
}

// ---------------------------------------------------------------------------
// Phase 2: one block per (b, strip): 512 blocks (2/CU), 8-row 8KB LDS tile,
// native integer atomics (ds_add_u32, fixed point 2^20), plain-store flush.
// ---------------------------------------------------------------------------
__global__ __launch_bounds__(1024) void k_deposit(
    const uint2* __restrict__ arena, const unsigned* __restrict__ gcnt,
    float* __restrict__ img) {
  __shared__ unsigned tile[kStripRows * kS];  // 8KB
  int tid = threadIdx.x;
  int b = blockIdx.x >> 5;
  int q = blockIdx.x & 31;
  for (int i = tid; i < kStripRows * kS; i += 1024) tile[i] = 0u;
  __syncthreads();
  unsigned cnt = gcnt[b * kNStrip + q];
  if (cnt > (unsigned)kCAP) cnt = kCAP;
  const uint2* rec = arena + (size_t)(b * kNStrip + q) * kCAP;
  for (unsigned i = tid; i < cnt; i += 1024) {
    uint2 r = rec[i];
    int x0 = (int)(r.x & 511u) - 1;
    int y0 = (int)((r.x >> 9) & 511u) - 1;
    float wx1 = (float)((r.x >> 18) & 2047u) * (1.f / 2048.f);
    float wy1 = (float)(((r.x >> 29) & 7u) | ((r.y & 255u) << 3)) * (1.f / 2048.f);
    float v = (float)(r.y >> 8) * (1.f / 16777216.f);
    float wx0 = 1.f - wx1, wy0 = 1.f - wy1;
#pragma unroll
    for (int dy = 0; dy < 2; ++dy) {
      int row = y0 + dy;
      if ((row >> 3) != q) continue;  // also rejects row<0 / row>255
      float wv = (dy ? wy1 : wy0) * v;
      int rr = (row & 7) * kS;
      if (x0 >= 0)
        atomicAdd(&tile[rr + x0], (unsigned)(wv * wx0 * kFxScale + 0.5f));
      if (x0 + 1 <= 255)
        atomicAdd(&tile[rr + x0 + 1], (unsigned)(wv * wx1 * kFxScale + 0.5f));
    }
  }
  __syncthreads();
  float* dst = img + (size_t)b * kS * kS + (size_t)q * kStripRows * kS;
  for (int i = tid; i < kStripRows * kS; i += 1024)
    dst[i] = (float)tile[i] * (1.f / kFxScale);
}

// ---------------------------------------------------------------------------
// Fallback: direct-atomic scatter (used only if ws_size is too small)
// ---------------------------------------------------------------------------
__global__ __launch_bounds__(256) void k_scatter(
    const float* __restrict__ proj, const float* __restrict__ Zvol,
    const float* __restrict__ coords, const float* __restrict__ values,
    float* __restrict__ img) {
  int tid = threadIdx.x;
  int n = blockIdx.x * 256 + tid;
  if (n >= kN) return;
  float Zv[kL];
  const float4* zrow = reinterpret_cast<const float4*>(Zvol + (size_t)n * kL);
#pragma unroll
  for (int q = 0; q < kL / 4; ++q) {
    float4 f = zrow[q];
    Zv[4 * q + 0] = f.x; Zv[4 * q + 1] = f.y;
    Zv[4 * q + 2] = f.z; Zv[4 * q + 3] = f.w;
  }
  float cx0 = coords[(size_t)n * 3 + 0];
  float cy0 = coords[(size_t)n * 3 + 1];
  float cz0 = coords[(size_t)n * 3 + 2];
  float v = values[n];
  for (int b = 0; b < kB; ++b) {
    const float* pb = proj + b * kProjStride;
    float fx = pb[72] * cx0 + pb[73] * cy0 + pb[74] * cz0 + pb[78];
    float fy = pb[75] * cx0 + pb[76] * cy0 + pb[77] * cz0 + pb[79];
#pragma unroll
    for (int l = 0; l < kL; ++l) {
      float zvl = Zv[l];
      fx = fmaf(pb[l], zvl, fx);
      fy = fmaf(pb[kL + l], zvl, fy);
    }
    float x0f = floorf(fx), y0f = floorf(fy);
    float wx1 = fx - x0f, wy1 = fy - y0f;
    float wx0 = 1.f - wx1, wy0 = 1.f - wy1;
    int x0 = (int)x0f, y0 = (int)y0f;
    float* imb = img + (size_t)b * kS * kS;
#pragma unroll
    for (int dyi = 0; dyi < 2; ++dyi) {
      int yi = y0 + dyi;
      if ((unsigned)yi >= (unsigned)kS) continue;
      float wy = dyi ? wy1 : wy0;
#pragma unroll
      for (int dxi = 0; dxi < 2; ++dxi) {
        int xi = x0 + dxi;
        if ((unsigned)xi >= (unsigned)kS) continue;
        float wx = dxi ? wx1 : wx0;
        unsafeAtomicAdd(imb + yi * kS + xi, wy * wx * v);
      }
    }
  }
}

// ---------------------------------------------------------------------------
// Atoms fallback (ws-small path) + fused bond/angle
// ---------------------------------------------------------------------------
__global__ __launch_bounds__(256) void k_atoms(
    const float* __restrict__ zx, const float* __restrict__ zy,
    const float* __restrict__ zz, const float* __restrict__ Za,
    const float* __restrict__ ac, float* __restrict__ atoms) {
  int i = blockIdx.x * 256 + threadIdx.x;
  if (i >= kNA) return;
  float Zv[kL];
  const float4* zrow = reinterpret_cast<const float4*>(Za + (size_t)i * kL);
#pragma unroll
  for (int q = 0; q < kL / 4; ++q) {
    float4 f = zrow[q];
    Zv[4 * q + 0] = f.x; Zv[4 * q + 1] = f.y;
    Zv[4 * q + 2] = f.z; Zv[4 * q + 3] = f.w;
  }
  float ax = ac[(size_t)i * 3 + 0];
  float ay = ac[(size_t)i * 3 + 1];
  float az = ac[(size_t)i * 3 + 2];
  for (int b = 0; b < kB; ++b) {
    float dx = 0.f, dy = 0.f, dz = 0.f;
#pragma unroll
    for (int l = 0; l < kL; ++l) {
      float zvl = Zv[l];
      dx = fmaf(zx[b * kL + l], zvl, dx);
      dy = fmaf(zy[b * kL + l], zvl, dy);
      dz = fmaf(zz[b * kL + l], zvl, dz);
    }
    size_t o = ((size_t)b * kNA + i) * 3;
    atoms[o + 0] = ax + dx;
    atoms[o + 1] = ay + dy;
    atoms[o + 2] = az + dz;
  }
}

__global__ __launch_bounds__(256) void k_bondangle(
    const float* __restrict__ atoms, const int* __restrict__ bidx,
    const int* __restrict__ aidx, float* __restrict__ out_bond,
    float* __restrict__ out_angle) {
  int t = blockIdx.x * 256 + threadIdx.x;
  if (t < kB * kNB) {
    int j = t % kNB;
    int b = t / kNB;
    int i0 = bidx[(size_t)j * 2 + 0];
    int i1 = bidx[(size_t)j * 2 + 1];
    const float* base = atoms + (size_t)b * kNA * 3;
    const float* p0 = base + (size_t)i0 * 3;
    const float* p1 = base + (size_t)i1 * 3;
    float dx = p0[0] - p1[0];
    float dy = p0[1] - p1[1];
    float dz = p0[2] - p1[2];
    out_bond[t] = sqrtf(dx * dx + dy * dy + dz * dz + 1e-12f);
    return;
  }
  t -= kB * kNB;
  if (t >= kB * kNC) return;
  int j = t % kNC;
  int b = t / kNC;
  int i0 = aidx[(size_t)j * 3 + 0];
  int i1 = aidx[(size_t)j * 3 + 1];
  int i2 = aidx[(size_t)j * 3 + 2];
  const float* base = atoms + (size_t)b * kNA * 3;
  const float* p0 = base + (size_t)i0 * 3;
  const float* p1 = base + (size_t)i1 * 3;
  const float* p2 = base + (size_t)i2 * 3;
  float ux = p0[0] - p1[0], uy = p0[1] - p1[1], uz = p0[2] - p1[2];
  float vx = p2[0] - p1[0], vy = p2[1] - p1[1], vz = p2[2] - p1[2];
  float uv = ux * vx + uy * vy + uz * vz;
  float uu = ux * ux + uy * uy + uz * uz;
  float vv = vx * vx + vy * vy + vz * vz;
  float c = uv / (sqrtf(uu * vv) + 1e-6f);
  c = fminf(0.999f, fmaxf(-0.999f, c));
  out_angle[t] = acosf(c);
}

// ---------------------------------------------------------------------------
// 256-point radix-2 DIT FFT, TWO LINES per 256-thread block.
// line l = tid>>7, lane t = tid&127. Every thread does 1 butterfly/stage.
// sign=-1 forward, +1 inverse (unnormalized).
// ---------------------------------------------------------------------------
__device__ __forceinline__ void fft256x2_lds(float (*re)[kS], float (*im)[kS],
                                             int l, int t, float sign) {
  unsigned r0 = __brev((unsigned)t) >> 24;
  float a0 = re[l][t], b0 = im[l][t];
  float a1 = re[l][t + 128], b1 = im[l][t + 128];
  __syncthreads();
  re[l][r0] = a0;
  im[l][r0] = b0;
  re[l][r0 + 1] = a1;
  im[l][r0 + 1] = b1;
  __syncthreads();
#pragma unroll
  for (int s = 1; s <= 8; ++s) {
    int half = 1 << (s - 1);
    int k = t & (half - 1);
    int i0 = ((t >> (s - 1)) << s) | k;
    int i1 = i0 + half;
    float ang = sign * (3.14159265358979f * (float)k / (float)half);
    float sn, cs;
    __sincosf(ang, &sn, &cs);
    float xr = re[l][i1], xi = im[l][i1];
    float tr = cs * xr - sn * xi;
    float ti = cs * xi + sn * xr;
    float ur = re[l][i0], ui = im[l][i0];
    re[l][i0] = ur + tr;
    im[l][i0] = ui + ti;
    re[l][i1] = ur - tr;
    im[l][i1] = ui - ti;
    __syncthreads();
  }
}

// Pass 1 (fused 5x5 Gaussian conv + forward row FFT), 2 lines (y, y+1)/block.
__global__ __launch_bounds__(256) void k_conv_fft_rows(
    const float* __restrict__ img, float* __restrict__ outRe,
    float* __restrict__ outIm) {
  __shared__ float rows[6][260];
  __shared__ float re[2][kS], im[2][kS];
  int tid = threadIdx.x;
  int blk = blockIdx.x;           // b*128 + y/2
  int b = blk >> 7, y0 = (blk & 127) * 2;
  const float* imb = img + (size_t)b * kS * kS;
#pragma unroll
  for (int r = 0; r < 6; ++r) {
    int yy = y0 + r - 2;
    rows[r][tid + 2] = ((unsigned)yy < (unsigned)kS) ? imb[yy * kS + tid] : 0.f;
  }
  if (tid < 2) {
#pragma unroll
    for (int r = 0; r < 6; ++r) {
      rows[r][tid] = 0.f;
      rows[r][258 + tid] = 0.f;
    }
  }
  __syncthreads();
  const float wt[5] = {0.05448868454f, 0.24420134723f, 0.40261993646f,
                       0.24420134723f, 0.05448868454f};
  int l = tid >> 7, t = tid & 127;
#pragma unroll
  for (int e = 0; e < 2; ++e) {
    int col = t + e * 128;
    float acc = 0.f;
#pragma unroll
    for (int r = 0; r < 5; ++r) {
      float rs = 0.f;
#pragma unroll
      for (int c = 0; c < 5; ++c) rs = fmaf(wt[c], rows[l + r][col + c], rs);
      acc = fmaf(wt[r], rs, acc);
    }
    re[l][col] = acc;
    im[l][col] = 0.f;
  }
  fft256x2_lds(re, im, l, t, -1.f);
  size_t ob = (size_t)b * kS * kS + (y0 + l);
  outRe[ob + (size_t)t * kS] = re[l][t];
  outIm[ob + (size_t)t * kS] = im[l][t];
  outRe[ob + (size_t)(t + 128) * kS] = re[l][t + 128];
  outIm[ob + (size_t)(t + 128) * kS] = im[l][t + 128];
}

// Pass 2: forward FFT over y, multiply by ctfT (coalesced), inverse FFT.
__global__ __launch_bounds__(256) void k_fft_cols(
    const float* __restrict__ inRe, const float* __restrict__ inIm,
    const float* __restrict__ ctfT, float* __restrict__ outRe,
    float* __restrict__ outIm) {
  __shared__ float re[2][kS], im[2][kS];
  int tid = threadIdx.x;
  int blk = blockIdx.x;           // b*128 + kx/2
  int b = blk >> 7, kx0 = (blk & 127) * 2;
  int l = tid >> 7, t = tid & 127;
  size_t base = ((size_t)b * kS + kx0 + l) * kS;
  re[l][t] = inRe[base + t];
  im[l][t] = inIm[base + t];
  re[l][t + 128] = inRe[base + t + 128];
  im[l][t + 128] = inIm[base + t + 128];
  fft256x2_lds(re, im, l, t, -1.f);
  float c0 = ctfT[base + t];
  float c1 = ctfT[base + t + 128];
  re[l][t] *= c0;
  im[l][t] *= c0;
  re[l][t + 128] *= c1;
  im[l][t + 128] *= c1;
  __syncthreads();
  fft256x2_lds(re, im, l, t, 1.f);
  size_t ob = (size_t)b * kS * kS + (kx0 + l);
  outRe[ob + (size_t)t * kS] = re[l][t] * (1.f / 256.f);
  outIm[ob + (size_t)t * kS] = im[l][t] * (1.f / 256.f);
  outRe[ob + (size_t)(t + 128) * kS] = re[l][t + 128] * (1.f / 256.f);
  outIm[ob + (size_t)(t + 128) * kS] = im[l][t + 128] * (1.f / 256.f);
}

// Pass 3: inverse FFT over x, real part -> out image. 2 y-lines per block.
__global__ __launch_bounds__(256) void k_fft_rows_inv(
    const float* __restrict__ inRe, const float* __restrict__ inIm,
    float* __restrict__ out) {
  __shared__ float re[2][kS], im[2][kS];
  int tid = threadIdx.x;
  int blk = blockIdx.x;           // b*128 + y/2
  int b = blk >> 7, y0 = (blk & 127) * 2;
  int l = tid >> 7, t = tid & 127;
  size_t base = ((size_t)b * kS + y0 + l) * kS;
  re[l][t] = inRe[base + t];
  im[l][t] = inIm[base + t];
  re[l][t + 128] = inRe[base + t + 128];
  im[l][t + 128] = inIm[base + t + 128];
  fft256x2_lds(re, im, l, t, 1.f);
  out[base + t] = re[l][t] * (1.f / 256.f);
  out[base + t + 128] = re[l][t + 128] * (1.f / 256.f);
}

// ---------------------------------------------------------------------------
extern "C" void kernel_launch(void* const* d_in, const int* in_sizes, int n_in,
                              void* d_out, int out_size, void* d_ws,
                              size_t ws_size, hipStream_t stream) {
  const float* zx     = (const float*)d_in[0];
  const float* zy     = (const float*)d_in[1];
  const float* zz     = (const float*)d_in[2];
  const float* de     = (const float*)d_in[3];
  const float* dsh    = (const float*)d_in[4];
  const float* Zvol   = (const float*)d_in[5];
  const float* Za     = (const float*)d_in[6];
  const float* coords = (const float*)d_in[7];
  const float* values = (const float*)d_in[8];
  const float* ac     = (const float*)d_in[9];
  const float* ctf    = (const float*)d_in[10];
  const int*   bidx   = (const int*)d_in[11];
  const int*   aidx   = (const int*)d_in[12];

  float* ws    = (float*)d_ws;
  float* imgA  = ws;                           // scatter target; later dIm
  float* imgB  = ws + kImgElems;               // later dRe
  float* cRe   = ws + 2 * (size_t)kImgElems;
  float* cIm   = ws + 3 * (size_t)kImgElems;
  float* atoms = ws + 4 * (size_t)kImgElems;   // B*NA*3 floats
  unsigned* gcnt = (unsigned*)(atoms + (size_t)kB * kNA * 3);  // 512 counters
  float* proj = (float*)(gcnt + kNCnt);        // kB*kProjStride floats
  uint2* arena = (uint2*)(proj + kB * kProjStride);
  size_t fixedBytes =
      (size_t)(4 * (size_t)kImgElems + (size_t)kB * kNA * 3 + kNCnt +
               kB * kProjStride) * 4;

  float* dRe = imgB;
  float* dIm = imgA;
  float* out_img   = (float*)d_out;
  float* out_bond  = out_img + kImgElems;
  float* out_angle = out_bond + (size_t)kB * kNB;
  // ctfT scratch lives in out_img: written by k_ctfT, read by k_fft_cols,
  // then overwritten by k_fft_rows_inv. Lifetimes do not overlap per-kernel.
  float* ctfT = out_img;

  size_t avail = (ws_size > fixedBytes) ? (ws_size - fixedBytes) : 0;
  bool full = ((size_t)kNCnt * kCAP * sizeof(uint2)) <= avail;

  {
    dim3 tg(8, 8, kB);
    k_ctfT<<<tg, 256, 0, stream>>>(ctf, ctfT, zx, zy, zz, de, dsh, proj);
  }

  if (full) {
    hipMemsetAsync(gcnt, 0, kNCnt * sizeof(unsigned), stream);
    k_project<<<kProjBlocks + kAtomBlocks, kPB, 0, stream>>>(
        proj, Zvol, coords, values, arena, gcnt, zx, zy, zz, Za, ac, atoms);
    k_deposit<<<kNCnt, 1024, 0, stream>>>(arena, gcnt, imgA);
  } else {
    hipMemsetAsync(imgA, 0, (size_t)kImgElems * sizeof(float), stream);
    k_scatter<<<(kN + 255) / 256, 256, 0, stream>>>(proj, Zvol, coords, values,
                                                    imgA);
    k_atoms<<<(kNA + 255) / 256, 256, 0, stream>>>(zx, zy, zz, Za, ac, atoms);
  }

  k_conv_fft_rows<<<kB * kS / 2, 256, 0, stream>>>(imgA, cRe, cIm);
  k_fft_cols<<<kB * kS / 2, 256, 0, stream>>>(cRe, cIm, ctfT, dRe, dIm);
  k_fft_rows_inv<<<kB * kS / 2, 256, 0, stream>>>(dRe, dIm, out_img);

  k_bondangle<<<(kB * (kNB + kNC) + 255) / 256, 256, 0, stream>>>(
      atoms, bidx, aidx, out_bond, out_angle);
}

// Round 17
// 185.620 us; speedup vs baseline: 1.0151x; 1.0151x over previous
//
#include <hip/hip_runtime.h>
#include <math.h>

// Problem constants (match reference)
constexpr int kS  = 256;
constexpr int kB  = 16;
constexpr int kL  = 36;
constexpr int kN  = 400000;
constexpr int kNA = 50000;
constexpr int kNB = 50000;
constexpr int kNC = 50000;

constexpr int kImgElems = kB * kS * kS;  // 1,048,576
constexpr int kNStrip = 16;              // strips per image (16 rows each)
constexpr int kStripRows = 16;
constexpr int kCAP = 32768;              // records per bucket (expected max ~28K)
constexpr float kFxScale = 1048576.f;    // 2^20 fixed-point scale for deposit
constexpr int kProjStride = 80;          // floats per b in proj table
constexpr int kPB = 256;                 // threads (points) per project block
constexpr int kProjBlocks = (kN + kPB - 1) / kPB;   // 1563
constexpr int kAtomBlocks = (kNA + kPB - 1) / kPB;  // 196

// ---------------------------------------------------------------------------
// ctf transpose (+ fused prep in block 0): ctfT[b][x][y] = ctf[b][y][x]
// ---------------------------------------------------------------------------
__global__ __launch_bounds__(256) void k_ctfT(
    const float* __restrict__ ctf, float* __restrict__ ctfT,
    const float* __restrict__ zx, const float* __restrict__ zy,
    const float* __restrict__ zz, const float* __restrict__ de,
    const float* __restrict__ dsh, float* __restrict__ proj) {
  __shared__ float tile[32][33];
  int b = blockIdx.z;
  int x0 = blockIdx.x * 32, y0 = blockIdx.y * 32;
  int tx = threadIdx.x & 31, ty4 = threadIdx.x >> 5;  // 32 x 8
  const float* src = ctf + (size_t)b * kS * kS;
  float* dst = ctfT + (size_t)b * kS * kS;
#pragma unroll
  for (int r = 0; r < 4; ++r) {
    int y = y0 + ty4 + r * 8;
    tile[ty4 + r * 8][tx] = src[y * kS + x0 + tx];
  }
  __syncthreads();
#pragma unroll
  for (int r = 0; r < 4; ++r) {
    int x = x0 + ty4 + r * 8;
    dst[(size_t)x * kS + y0 + tx] = tile[tx][ty4 + r * 8];
  }
  // fused prep: per-b combined projection weights (block 0 only)
  if (b == 0 && blockIdx.x == 0 && blockIdx.y == 0 && threadIdx.x < kB) {
    int pbi = threadIdx.x;
    float a = de[pbi * 3 + 0], bb = de[pbi * 3 + 1], g = de[pbi * 3 + 2];
    float ca, sa, cb, sb, cg, sg;
    sincosf(a, &sa, &ca);
    sincosf(bb, &sb, &cb);
    sincosf(g, &sg, &cg);
    float R0 = cg * cb * ca - sg * sa;
    float R1 = cg * cb * sa + sg * ca;
    float R2 = -cg * sb;
    float R3 = -sg * cb * ca - cg * sa;
    float R4 = -sg * cb * sa + cg * ca;
    float R5 = sg * sb;
    float* p = proj + pbi * kProjStride;
    for (int l = 0; l < kL; ++l) {
      float x = zx[pbi * kL + l], y = zy[pbi * kL + l], z = zz[pbi * kL + l];
      p[l]      = R0 * x + R1 * y + R2 * z;
      p[kL + l] = R3 * x + R4 * y + R5 * z;
    }
    p[72] = R0; p[73] = R1; p[74] = R2;
    p[75] = R3; p[76] = R4; p[77] = R5;
    p[78] = dsh[pbi * 2 + 0] + 128.0f;
    p[79] = dsh[pbi * 2 + 1] + 128.0f;
  }
}

// ---------------------------------------------------------------------------
// Phase 1: project (+ fused atoms in trailing blocks). ROUND-15 VERIFIED FORM
// (183.5us total best): 256 thr/block, 1 point/thread, all 16 b's, VGPR 64.
// ---------------------------------------------------------------------------
__global__ __launch_bounds__(kPB, 2) void k_project(
    const float* __restrict__ proj, const float* __restrict__ Zvol,
    const float* __restrict__ coords, const float* __restrict__ values,
    uint2* __restrict__ arena, unsigned* __restrict__ gcnt,
    const float* __restrict__ zx, const float* __restrict__ zy,
    const float* __restrict__ zz, const float* __restrict__ Za,
    const float* __restrict__ ac, float* __restrict__ atoms) {
  int tid = threadIdx.x;

  if (blockIdx.x >= kProjBlocks) {
    // ------------------ fused k_atoms path ------------------
    int i = (blockIdx.x - kProjBlocks) * kPB + tid;
    if (i >= kNA) return;
    float Zv[kL];
    const float4* zrow = reinterpret_cast<const float4*>(Za + (size_t)i * kL);
#pragma unroll
    for (int q = 0; q < kL / 4; ++q) {
      float4 f = zrow[q];
      Zv[4 * q + 0] = f.x; Zv[4 * q + 1] = f.y;
      Zv[4 * q + 2] = f.z; Zv[4 * q + 3] = f.w;
    }
    float ax = ac[(size_t)i * 3 + 0];
    float ay = ac[(size_t)i * 3 + 1];
    float az = ac[(size_t)i * 3 + 2];
    for (int b = 0; b < kB; ++b) {
      float dx = 0.f, dy = 0.f, dz = 0.f;
#pragma unroll
      for (int l = 0; l < kL; ++l) {
        float zvl = Zv[l];
        dx = fmaf(zx[b * kL + l], zvl, dx);
        dy = fmaf(zy[b * kL + l], zvl, dy);
        dz = fmaf(zz[b * kL + l], zvl, dz);
      }
      size_t o = ((size_t)b * kNA + i) * 3;
      atoms[o + 0] = ax + dx;
      atoms[o + 1] = ay + dy;
      atoms[o + 2] = az + dz;
    }
    return;
  }

  // ------------------ project path (round-8/11 verified form) ---------------
  __shared__ unsigned s_cnt[kB * kNStrip];  // 256 counters
  __shared__ unsigned s_base[kB * kNStrip];
  s_cnt[tid] = 0u;

  int n = blockIdx.x * kPB + tid;
  bool act = n < kN;
  float Zv[kL];
  float cx0 = 0.f, cy0 = 0.f, cz0 = 0.f, v = 0.f;
  if (act) {
    const float4* zrow = reinterpret_cast<const float4*>(Zvol + (size_t)n * kL);
#pragma unroll
    for (int q = 0; q < kL / 4; ++q) {
      float4 f = zrow[q];
      Zv[4 * q + 0] = f.x; Zv[4 * q + 1] = f.y;
      Zv[4 * q + 2] = f.z; Zv[4 * q + 3] = f.w;
    }
    cx0 = coords[(size_t)n * 3 + 0];
    cy0 = coords[(size_t)n * 3 + 1];
    cz0 = coords[(size_t)n * 3 + 2];
    v = values[n];
  }
  unsigned qv = (unsigned)(v * 16777216.f);
  if (qv > 16777215u) qv = 16777215u;
  __syncthreads();  // counters zeroed

  int fxq[kB], fyq[kB];
  unsigned flags = 0;

  // pass 1: compute + count
#pragma unroll
  for (int b = 0; b < kB; ++b) {
    const float* pb = proj + b * kProjStride;  // uniform -> s_loads
    float fx = pb[72] * cx0 + pb[73] * cy0 + pb[74] * cz0 + pb[78];
    float fy = pb[75] * cx0 + pb[76] * cy0 + pb[77] * cz0 + pb[79];
#pragma unroll
    for (int l = 0; l < kL; ++l) {
      float zvl = Zv[l];
      fx = fmaf(pb[l], zvl, fx);
      fy = fmaf(pb[kL + l], zvl, fy);
    }
    int xq = (int)floorf(fx * 2048.f);
    int yq = (int)floorf(fy * 2048.f);
    fxq[b] = xq;
    fyq[b] = yq;
    int x0 = xq >> 11, y0 = yq >> 11;
    if (act && x0 >= -1 && x0 <= 255 && y0 >= -1 && y0 <= 255) {
      flags |= 1u << b;
      int q0 = y0 >> 4;        // may be -1
      int q1 = (y0 + 1) >> 4;  // 0..16
      if (q0 >= 0) atomicAdd(&s_cnt[b * kNStrip + q0], 1u);
      if (q1 <= 15 && q1 != q0) atomicAdd(&s_cnt[b * kNStrip + q1], 1u);
    }
  }
  __syncthreads();

  // reserve: one concurrent global atomic round, one counter per thread
  {
    unsigned cnt = s_cnt[tid];
    s_base[tid] = cnt ? atomicAdd(&gcnt[tid], cnt) : 0u;
    s_cnt[tid] = 0u;  // reset for slot pass
  }
  __syncthreads();

  // pass 2: slots + writes (no trailing barrier; stores drain at kernel end)
#pragma unroll
  for (int b = 0; b < kB; ++b) {
    if (!((flags >> b) & 1u)) continue;
    int xq = fxq[b], yq = fyq[b];
    int x0 = xq >> 11, y0 = yq >> 11;
    unsigned qwx = (unsigned)(xq & 2047), qwy = (unsigned)(yq & 2047);
    uint2 rec;
    rec.x = (unsigned)(x0 + 1) | ((unsigned)(y0 + 1) << 9) | (qwx << 18) |
            ((qwy & 7u) << 29);
    rec.y = (qwy >> 3) | (qv << 8);
    int q0 = y0 >> 4;
    int q1 = (y0 + 1) >> 4;
    if (q0 >= 0) {
      int c = b * kNStrip + q0;
      unsigned sl = atomicAdd(&s_cnt[c], 1u);
      unsigned idx = s_base[c] + sl;
      if (idx < (unsigned)kCAP) arena[(size_t)c * kCAP + idx] = rec;
    }
    if (q1 <= 15 && q1 != q0) {
      int c = b * kNStrip + q1;
      unsigned sl = atomicAdd(&s_cnt[c], 1u);
      unsigned idx = s_base[c] + sl;
      if (idx < (unsigned)kCAP) arena[(size_t)c * kCAP + idx] = rec;
    }
  }
}

// ---------------------------------------------------------------------------
// Phase 2: one block per (b, strip): accumulate records into LDS tile with
// native integer atomics (ds_add_u32, fixed point 2^20), flush plain stores.
// ---------------------------------------------------------------------------
__global__ __launch_bounds__(1024) void k_deposit(
    const uint2* __restrict__ arena, const unsigned* __restrict__ gcnt,
    float* __restrict__ img) {
  __shared__ unsigned tile[kStripRows * kS];  // 16KB
  int tid = threadIdx.x;
  int b = blockIdx.x >> 4;
  int q = blockIdx.x & 15;
  for (int i = tid; i < kStripRows * kS; i += 1024) tile[i] = 0u;
  __syncthreads();
  unsigned cnt = gcnt[b * kNStrip + q];
  if (cnt > (unsigned)kCAP) cnt = kCAP;
  const uint2* rec = arena + (size_t)(b * kNStrip + q) * kCAP;
  for (unsigned i = tid; i < cnt; i += 1024) {
    uint2 r = rec[i];
    int x0 = (int)(r.x & 511u) - 1;
    int y0 = (int)((r.x >> 9) & 511u) - 1;
    float wx1 = (float)((r.x >> 18) & 2047u) * (1.f / 2048.f);
    float wy1 = (float)(((r.x >> 29) & 7u) | ((r.y & 255u) << 3)) * (1.f / 2048.f);
    float v = (float)(r.y >> 8) * (1.f / 16777216.f);
    float wx0 = 1.f - wx1, wy0 = 1.f - wy1;
#pragma unroll
    for (int dy = 0; dy < 2; ++dy) {
      int row = y0 + dy;
      if ((row >> 4) != q) continue;  // also rejects row<0 / row>255
      float wv = (dy ? wy1 : wy0) * v;
      int rr = (row & 15) * kS;
      if (x0 >= 0)
        atomicAdd(&tile[rr + x0], (unsigned)(wv * wx0 * kFxScale + 0.5f));
      if (x0 + 1 <= 255)
        atomicAdd(&tile[rr + x0 + 1], (unsigned)(wv * wx1 * kFxScale + 0.5f));
    }
  }
  __syncthreads();
  float* dst = img + (size_t)b * kS * kS + (size_t)q * kStripRows * kS;
  for (int i = tid; i < kStripRows * kS; i += 1024)
    dst[i] = (float)tile[i] * (1.f / kFxScale);
}

// ---------------------------------------------------------------------------
// Fallback: direct-atomic scatter (used only if ws_size is too small)
// ---------------------------------------------------------------------------
__global__ __launch_bounds__(256) void k_scatter(
    const float* __restrict__ proj, const float* __restrict__ Zvol,
    const float* __restrict__ coords, const float* __restrict__ values,
    float* __restrict__ img) {
  int tid = threadIdx.x;
  int n = blockIdx.x * 256 + tid;
  if (n >= kN) return;
  float Zv[kL];
  const float4* zrow = reinterpret_cast<const float4*>(Zvol + (size_t)n * kL);
#pragma unroll
  for (int q = 0; q < kL / 4; ++q) {
    float4 f = zrow[q];
    Zv[4 * q + 0] = f.x; Zv[4 * q + 1] = f.y;
    Zv[4 * q + 2] = f.z; Zv[4 * q + 3] = f.w;
  }
  float cx0 = coords[(size_t)n * 3 + 0];
  float cy0 = coords[(size_t)n * 3 + 1];
  float cz0 = coords[(size_t)n * 3 + 2];
  float v = values[n];
  for (int b = 0; b < kB; ++b) {
    const float* pb = proj + b * kProjStride;
    float fx = pb[72] * cx0 + pb[73] * cy0 + pb[74] * cz0 + pb[78];
    float fy = pb[75] * cx0 + pb[76] * cy0 + pb[77] * cz0 + pb[79];
#pragma unroll
    for (int l = 0; l < kL; ++l) {
      float zvl = Zv[l];
      fx = fmaf(pb[l], zvl, fx);
      fy = fmaf(pb[kL + l], zvl, fy);
    }
    float x0f = floorf(fx), y0f = floorf(fy);
    float wx1 = fx - x0f, wy1 = fy - y0f;
    float wx0 = 1.f - wx1, wy0 = 1.f - wy1;
    int x0 = (int)x0f, y0 = (int)y0f;
    float* imb = img + (size_t)b * kS * kS;
#pragma unroll
    for (int dyi = 0; dyi < 2; ++dyi) {
      int yi = y0 + dyi;
      if ((unsigned)yi >= (unsigned)kS) continue;
      float wy = dyi ? wy1 : wy0;
#pragma unroll
      for (int dxi = 0; dxi < 2; ++dxi) {
        int xi = x0 + dxi;
        if ((unsigned)xi >= (unsigned)kS) continue;
        float wx = dxi ? wx1 : wx0;
        unsafeAtomicAdd(imb + yi * kS + xi, wy * wx * v);
      }
    }
  }
}

// ---------------------------------------------------------------------------
// Atoms fallback (ws-small path) + fused bond/angle
// ---------------------------------------------------------------------------
__global__ __launch_bounds__(256) void k_atoms(
    const float* __restrict__ zx, const float* __restrict__ zy,
    const float* __restrict__ zz, const float* __restrict__ Za,
    const float* __restrict__ ac, float* __restrict__ atoms) {
  int i = blockIdx.x * 256 + threadIdx.x;
  if (i >= kNA) return;
  float Zv[kL];
  const float4* zrow = reinterpret_cast<const float4*>(Za + (size_t)i * kL);
#pragma unroll
  for (int q = 0; q < kL / 4; ++q) {
    float4 f = zrow[q];
    Zv[4 * q + 0] = f.x; Zv[4 * q + 1] = f.y;
    Zv[4 * q + 2] = f.z; Zv[4 * q + 3] = f.w;
  }
  float ax = ac[(size_t)i * 3 + 0];
  float ay = ac[(size_t)i * 3 + 1];
  float az = ac[(size_t)i * 3 + 2];
  for (int b = 0; b < kB; ++b) {
    float dx = 0.f, dy = 0.f, dz = 0.f;
#pragma unroll
    for (int l = 0; l < kL; ++l) {
      float zvl = Zv[l];
      dx = fmaf(zx[b * kL + l], zvl, dx);
      dy = fmaf(zy[b * kL + l], zvl, dy);
      dz = fmaf(zz[b * kL + l], zvl, dz);
    }
    size_t o = ((size_t)b * kNA + i) * 3;
    atoms[o + 0] = ax + dx;
    atoms[o + 1] = ay + dy;
    atoms[o + 2] = az + dz;
  }
}

__global__ __launch_bounds__(256) void k_bondangle(
    const float* __restrict__ atoms, const int* __restrict__ bidx,
    const int* __restrict__ aidx, float* __restrict__ out_bond,
    float* __restrict__ out_angle) {
  int t = blockIdx.x * 256 + threadIdx.x;
  if (t < kB * kNB) {
    int j = t % kNB;
    int b = t / kNB;
    int i0 = bidx[(size_t)j * 2 + 0];
    int i1 = bidx[(size_t)j * 2 + 1];
    const float* base = atoms + (size_t)b * kNA * 3;
    const float* p0 = base + (size_t)i0 * 3;
    const float* p1 = base + (size_t)i1 * 3;
    float dx = p0[0] - p1[0];
    float dy = p0[1] - p1[1];
    float dz = p0[2] - p1[2];
    out_bond[t] = sqrtf(dx * dx + dy * dy + dz * dz + 1e-12f);
    return;
  }
  t -= kB * kNB;
  if (t >= kB * kNC) return;
  int j = t % kNC;
  int b = t / kNC;
  int i0 = aidx[(size_t)j * 3 + 0];
  int i1 = aidx[(size_t)j * 3 + 1];
  int i2 = aidx[(size_t)j * 3 + 2];
  const float* base = atoms + (size_t)b * kNA * 3;
  const float* p0 = base + (size_t)i0 * 3;
  const float* p1 = base + (size_t)i1 * 3;
  const float* p2 = base + (size_t)i2 * 3;
  float ux = p0[0] - p1[0], uy = p0[1] - p1[1], uz = p0[2] - p1[2];
  float vx = p2[0] - p1[0], vy = p2[1] - p1[1], vz = p2[2] - p1[2];
  float uv = ux * vx + uy * vy + uz * vz;
  float uu = ux * ux + uy * uy + uz * uz;
  float vv = vx * vx + vy * vy + vz * vz;
  float c = uv / (sqrtf(uu * vv) + 1e-6f);
  c = fminf(0.999f, fmaxf(-0.999f, c));
  out_angle[t] = acosf(c);
}

// ---------------------------------------------------------------------------
// 256-point radix-2 DIT FFT, TWO LINES per 256-thread block.
// line l = tid>>7, lane t = tid&127. Every thread does 1 butterfly/stage.
// sign=-1 forward, +1 inverse (unnormalized).
// ---------------------------------------------------------------------------
__device__ __forceinline__ void fft256x2_lds(float (*re)[kS], float (*im)[kS],
                                             int l, int t, float sign) {
  unsigned r0 = __brev((unsigned)t) >> 24;
  float a0 = re[l][t], b0 = im[l][t];
  float a1 = re[l][t + 128], b1 = im[l][t + 128];
  __syncthreads();
  re[l][r0] = a0;
  im[l][r0] = b0;
  re[l][r0 + 1] = a1;
  im[l][r0 + 1] = b1;
  __syncthreads();
#pragma unroll
  for (int s = 1; s <= 8; ++s) {
    int half = 1 << (s - 1);
    int k = t & (half - 1);
    int i0 = ((t >> (s - 1)) << s) | k;
    int i1 = i0 + half;
    float ang = sign * (3.14159265358979f * (float)k / (float)half);
    float sn, cs;
    __sincosf(ang, &sn, &cs);
    float xr = re[l][i1], xi = im[l][i1];
    float tr = cs * xr - sn * xi;
    float ti = cs * xi + sn * xr;
    float ur = re[l][i0], ui = im[l][i0];
    re[l][i0] = ur + tr;
    im[l][i0] = ui + ti;
    re[l][i1] = ur - tr;
    im[l][i1] = ui - ti;
    __syncthreads();
  }
}

// Pass 1 (fused 5x5 Gaussian conv + forward row FFT), 2 lines (y, y+1)/block.
__global__ __launch_bounds__(256) void k_conv_fft_rows(
    const float* __restrict__ img, float* __restrict__ outRe,
    float* __restrict__ outIm) {
  __shared__ float rows[6][260];
  __shared__ float re[2][kS], im[2][kS];
  int tid = threadIdx.x;
  int blk = blockIdx.x;           // b*128 + y/2
  int b = blk >> 7, y0 = (blk & 127) * 2;
  const float* imb = img + (size_t)b * kS * kS;
#pragma unroll
  for (int r = 0; r < 6; ++r) {
    int yy = y0 + r - 2;
    rows[r][tid + 2] = ((unsigned)yy < (unsigned)kS) ? imb[yy * kS + tid] : 0.f;
  }
  if (tid < 2) {
#pragma unroll
    for (int r = 0; r < 6; ++r) {
      rows[r][tid] = 0.f;
      rows[r][258 + tid] = 0.f;
    }
  }
  __syncthreads();
  const float wt[5] = {0.05448868454f, 0.24420134723f, 0.40261993646f,
                       0.24420134723f, 0.05448868454f};
  int l = tid >> 7, t = tid & 127;
#pragma unroll
  for (int e = 0; e < 2; ++e) {
    int col = t + e * 128;
    float acc = 0.f;
#pragma unroll
    for (int r = 0; r < 5; ++r) {
      float rs = 0.f;
#pragma unroll
      for (int c = 0; c < 5; ++c) rs = fmaf(wt[c], rows[l + r][col + c], rs);
      acc = fmaf(wt[r], rs, acc);
    }
    re[l][col] = acc;
    im[l][col] = 0.f;
  }
  fft256x2_lds(re, im, l, t, -1.f);
  size_t ob = (size_t)b * kS * kS + (y0 + l);
  outRe[ob + (size_t)t * kS] = re[l][t];
  outIm[ob + (size_t)t * kS] = im[l][t];
  outRe[ob + (size_t)(t + 128) * kS] = re[l][t + 128];
  outIm[ob + (size_t)(t + 128) * kS] = im[l][t + 128];
}

// Pass 2: forward FFT over y, multiply by ctfT (coalesced), inverse FFT.
// NOTE: no barrier between the ctf multiply and the inverse FFT — each thread
// multiplies exactly the elements (l,t)/(l,t+128) that it alone re-reads at
// the start of fft256x2_lds; the first cross-thread write there is already
// behind that helper's internal barrier.
__global__ __launch_bounds__(256) void k_fft_cols(
    const float* __restrict__ inRe, const float* __restrict__ inIm,
    const float* __restrict__ ctfT, float* __restrict__ outRe,
    float* __restrict__ outIm) {
  __shared__ float re[2][kS], im[2][kS];
  int tid = threadIdx.x;
  int blk = blockIdx.x;           // b*128 + kx/2
  int b = blk >> 7, kx0 = (blk & 127) * 2;
  int l = tid >> 7, t = tid & 127;
  size_t base = ((size_t)b * kS + kx0 + l) * kS;
  re[l][t] = inRe[base + t];
  im[l][t] = inIm[base + t];
  re[l][t + 128] = inRe[base + t + 128];
  im[l][t + 128] = inIm[base + t + 128];
  fft256x2_lds(re, im, l, t, -1.f);
  float c0 = ctfT[base + t];
  float c1 = ctfT[base + t + 128];
  re[l][t] *= c0;
  im[l][t] *= c0;
  re[l][t + 128] *= c1;
  im[l][t + 128] *= c1;
  fft256x2_lds(re, im, l, t, 1.f);
  size_t ob = (size_t)b * kS * kS + (kx0 + l);
  outRe[ob + (size_t)t * kS] = re[l][t] * (1.f / 256.f);
  outIm[ob + (size_t)t * kS] = im[l][t] * (1.f / 256.f);
  outRe[ob + (size_t)(t + 128) * kS] = re[l][t + 128] * (1.f / 256.f);
  outIm[ob + (size_t)(t + 128) * kS] = im[l][t + 128] * (1.f / 256.f);
}

// Pass 3: inverse FFT over x, real part -> out image. 2 y-lines per block.
__global__ __launch_bounds__(256) void k_fft_rows_inv(
    const float* __restrict__ inRe, const float* __restrict__ inIm,
    float* __restrict__ out) {
  __shared__ float re[2][kS], im[2][kS];
  int tid = threadIdx.x;
  int blk = blockIdx.x;           // b*128 + y/2
  int b = blk >> 7, y0 = (blk & 127) * 2;
  int l = tid >> 7, t = tid & 127;
  size_t base = ((size_t)b * kS + y0 + l) * kS;
  re[l][t] = inRe[base + t];
  im[l][t] = inIm[base + t];
  re[l][t + 128] = inRe[base + t + 128];
  im[l][t + 128] = inIm[base + t + 128];
  fft256x2_lds(re, im, l, t, 1.f);
  out[base + t] = re[l][t] * (1.f / 256.f);
  out[base + t + 128] = re[l][t + 128] * (1.f / 256.f);
}

// ---------------------------------------------------------------------------
extern "C" void kernel_launch(void* const* d_in, const int* in_sizes, int n_in,
                              void* d_out, int out_size, void* d_ws,
                              size_t ws_size, hipStream_t stream) {
  const float* zx     = (const float*)d_in[0];
  const float* zy     = (const float*)d_in[1];
  const float* zz     = (const float*)d_in[2];
  const float* de     = (const float*)d_in[3];
  const float* dsh    = (const float*)d_in[4];
  const float* Zvol   = (const float*)d_in[5];
  const float* Za     = (const float*)d_in[6];
  const float* coords = (const float*)d_in[7];
  const float* values = (const float*)d_in[8];
  const float* ac     = (const float*)d_in[9];
  const float* ctf    = (const float*)d_in[10];
  const int*   bidx   = (const int*)d_in[11];
  const int*   aidx   = (const int*)d_in[12];

  float* ws    = (float*)d_ws;
  float* imgA  = ws;                           // scatter target; later dIm
  float* imgB  = ws + kImgElems;               // later dRe
  float* cRe   = ws + 2 * (size_t)kImgElems;
  float* cIm   = ws + 3 * (size_t)kImgElems;
  float* atoms = ws + 4 * (size_t)kImgElems;   // B*NA*3 floats
  unsigned* gcnt = (unsigned*)(atoms + (size_t)kB * kNA * 3);  // 256 counters
  float* proj = (float*)(gcnt + 256);          // kB*kProjStride floats
  uint2* arena = (uint2*)(proj + kB * kProjStride);
  size_t fixedBytes =
      (size_t)(4 * (size_t)kImgElems + (size_t)kB * kNA * 3 + 256 +
               kB * kProjStride) * 4;

  float* dRe = imgB;
  float* dIm = imgA;
  float* out_img   = (float*)d_out;
  float* out_bond  = out_img + kImgElems;
  float* out_angle = out_bond + (size_t)kB * kNB;
  // ctfT scratch lives in out_img: written by k_ctfT, read by k_fft_cols,
  // then overwritten by k_fft_rows_inv. Lifetimes do not overlap per-kernel.
  float* ctfT = out_img;

  size_t avail = (ws_size > fixedBytes) ? (ws_size - fixedBytes) : 0;
  bool full = ((size_t)kB * kNStrip * kCAP * sizeof(uint2)) <= avail;

  {
    dim3 tg(8, 8, kB);
    k_ctfT<<<tg, 256, 0, stream>>>(ctf, ctfT, zx, zy, zz, de, dsh, proj);
  }

  if (full) {
    hipMemsetAsync(gcnt, 0, 256 * sizeof(unsigned), stream);
    k_project<<<kProjBlocks + kAtomBlocks, kPB, 0, stream>>>(
        proj, Zvol, coords, values, arena, gcnt, zx, zy, zz, Za, ac, atoms);
    k_deposit<<<kB * kNStrip, 1024, 0, stream>>>(arena, gcnt, imgA);
  } else {
    hipMemsetAsync(imgA, 0, (size_t)kImgElems * sizeof(float), stream);
    k_scatter<<<(kN + 255) / 256, 256, 0, stream>>>(proj, Zvol, coords, values,
                                                    imgA);
    k_atoms<<<(kNA + 255) / 256, 256, 0, stream>>>(zx, zy, zz, Za, ac, atoms);
  }

  k_conv_fft_rows<<<kB * kS / 2, 256, 0, stream>>>(imgA, cRe, cIm);
  k_fft_cols<<<kB * kS / 2, 256, 0, stream>>>(cRe, cIm, ctfT, dRe, dIm);
  k_fft_rows_inv<<<kB * kS / 2, 256, 0, stream>>>(dRe, dIm, out_img);

  k_bondangle<<<(kB * (kNB + kNC) + 255) / 256, 256, 0, stream>>>(
      atoms, bidx, aidx, out_bond, out_angle);
}

// Round 18
// 160.740 us; speedup vs baseline: 1.1722x; 1.1548x over previous
//
#include <hip/hip_runtime.h>
#include <math.h>

// Problem constants (match reference)
constexpr int kS  = 256;
constexpr int kB  = 16;
constexpr int kL  = 36;
constexpr int kN  = 400000;
constexpr int kNA = 50000;
constexpr int kNB = 50000;
constexpr int kNC = 50000;

constexpr int kImgElems = kB * kS * kS;  // 1,048,576
constexpr int kNStrip = 16;              // strips per image (16 rows each)
constexpr int kStripRows = 16;
constexpr int kCAP = 32768;              // records per bucket (expected max ~28K)
constexpr float kFxScale = 1048576.f;    // 2^20 fixed-point scale for deposit
constexpr int kProjStride = 80;          // floats per b in proj table
constexpr int kPB = 256;                 // threads (points) per project block
constexpr int kProjBlocks = (kN + kPB - 1) / kPB;   // 1563
constexpr int kAtomBlocks = (kNA + kPB - 1) / kPB;  // 196

// ---------------------------------------------------------------------------
// ctf transpose (+ fused prep in block 0): ctfT[b][x][y] = ctf[b][y][x]
// ---------------------------------------------------------------------------
__global__ __launch_bounds__(256) void k_ctfT(
    const float* __restrict__ ctf, float* __restrict__ ctfT,
    const float* __restrict__ zx, const float* __restrict__ zy,
    const float* __restrict__ zz, const float* __restrict__ de,
    const float* __restrict__ dsh, float* __restrict__ proj) {
  __shared__ float tile[32][33];
  int b = blockIdx.z;
  int x0 = blockIdx.x * 32, y0 = blockIdx.y * 32;
  int tx = threadIdx.x & 31, ty4 = threadIdx.x >> 5;  // 32 x 8
  const float* src = ctf + (size_t)b * kS * kS;
  float* dst = ctfT + (size_t)b * kS * kS;
#pragma unroll
  for (int r = 0; r < 4; ++r) {
    int y = y0 + ty4 + r * 8;
    tile[ty4 + r * 8][tx] = src[y * kS + x0 + tx];
  }
  __syncthreads();
#pragma unroll
  for (int r = 0; r < 4; ++r) {
    int x = x0 + ty4 + r * 8;
    dst[(size_t)x * kS + y0 + tx] = tile[tx][ty4 + r * 8];
  }
  // fused prep: per-b combined projection weights (block 0 only)
  if (b == 0 && blockIdx.x == 0 && blockIdx.y == 0 && threadIdx.x < kB) {
    int pbi = threadIdx.x;
    float a = de[pbi * 3 + 0], bb = de[pbi * 3 + 1], g = de[pbi * 3 + 2];
    float ca, sa, cb, sb, cg, sg;
    sincosf(a, &sa, &ca);
    sincosf(bb, &sb, &cb);
    sincosf(g, &sg, &cg);
    float R0 = cg * cb * ca - sg * sa;
    float R1 = cg * cb * sa + sg * ca;
    float R2 = -cg * sb;
    float R3 = -sg * cb * ca - cg * sa;
    float R4 = -sg * cb * sa + cg * ca;
    float R5 = sg * sb;
    float* p = proj + pbi * kProjStride;
    for (int l = 0; l < kL; ++l) {
      float x = zx[pbi * kL + l], y = zy[pbi * kL + l], z = zz[pbi * kL + l];
      p[l]      = R0 * x + R1 * y + R2 * z;
      p[kL + l] = R3 * x + R4 * y + R5 * z;
    }
    p[72] = R0; p[73] = R1; p[74] = R2;
    p[75] = R3; p[76] = R4; p[77] = R5;
    p[78] = dsh[pbi * 2 + 0] + 128.0f;
    p[79] = dsh[pbi * 2 + 1] + 128.0f;
  }
}

// ---------------------------------------------------------------------------
// Phase 1: project + fused atoms. ATOMS BLOCKS FIRST (blockIdx < kAtomBlocks)
// so they co-run with the project wave instead of forming a <1-block/CU
// serial drain tail at the end of the dispatch.
// Project path: round-15 verified form (256 thr/block, 1 point/thread,
// all 16 b's, VGPR 64, no spill).
// Record (8B): x0+1:9 | y0+1:9 | qwx:11 | qwy:11 | qv:24
// ---------------------------------------------------------------------------
__global__ __launch_bounds__(kPB, 2) void k_project(
    const float* __restrict__ proj, const float* __restrict__ Zvol,
    const float* __restrict__ coords, const float* __restrict__ values,
    uint2* __restrict__ arena, unsigned* __restrict__ gcnt,
    const float* __restrict__ zx, const float* __restrict__ zy,
    const float* __restrict__ zz, const float* __restrict__ Za,
    const float* __restrict__ ac, float* __restrict__ atoms) {
  int tid = threadIdx.x;

  if (blockIdx.x < kAtomBlocks) {
    // ------------------ fused k_atoms path (runs FIRST) ------------------
    int i = blockIdx.x * kPB + tid;
    if (i >= kNA) return;
    float Zv[kL];
    const float4* zrow = reinterpret_cast<const float4*>(Za + (size_t)i * kL);
#pragma unroll
    for (int q = 0; q < kL / 4; ++q) {
      float4 f = zrow[q];
      Zv[4 * q + 0] = f.x; Zv[4 * q + 1] = f.y;
      Zv[4 * q + 2] = f.z; Zv[4 * q + 3] = f.w;
    }
    float ax = ac[(size_t)i * 3 + 0];
    float ay = ac[(size_t)i * 3 + 1];
    float az = ac[(size_t)i * 3 + 2];
    for (int b = 0; b < kB; ++b) {
      float dx = 0.f, dy = 0.f, dz = 0.f;
#pragma unroll
      for (int l = 0; l < kL; ++l) {
        float zvl = Zv[l];
        dx = fmaf(zx[b * kL + l], zvl, dx);
        dy = fmaf(zy[b * kL + l], zvl, dy);
        dz = fmaf(zz[b * kL + l], zvl, dz);
      }
      size_t o = ((size_t)b * kNA + i) * 3;
      atoms[o + 0] = ax + dx;
      atoms[o + 1] = ay + dy;
      atoms[o + 2] = az + dz;
    }
    return;
  }

  // ------------------ project path (round-15 verified form) -----------------
  __shared__ unsigned s_cnt[kB * kNStrip];  // 256 counters
  __shared__ unsigned s_base[kB * kNStrip];
  s_cnt[tid] = 0u;

  int n = (blockIdx.x - kAtomBlocks) * kPB + tid;
  bool act = n < kN;
  float Zv[kL];
  float cx0 = 0.f, cy0 = 0.f, cz0 = 0.f, v = 0.f;
  if (act) {
    const float4* zrow = reinterpret_cast<const float4*>(Zvol + (size_t)n * kL);
#pragma unroll
    for (int q = 0; q < kL / 4; ++q) {
      float4 f = zrow[q];
      Zv[4 * q + 0] = f.x; Zv[4 * q + 1] = f.y;
      Zv[4 * q + 2] = f.z; Zv[4 * q + 3] = f.w;
    }
    cx0 = coords[(size_t)n * 3 + 0];
    cy0 = coords[(size_t)n * 3 + 1];
    cz0 = coords[(size_t)n * 3 + 2];
    v = values[n];
  }
  unsigned qv = (unsigned)(v * 16777216.f);
  if (qv > 16777215u) qv = 16777215u;
  __syncthreads();  // counters zeroed

  int fxq[kB], fyq[kB];
  unsigned flags = 0;

  // pass 1: compute + count
#pragma unroll
  for (int b = 0; b < kB; ++b) {
    const float* pb = proj + b * kProjStride;  // uniform -> s_loads
    float fx = pb[72] * cx0 + pb[73] * cy0 + pb[74] * cz0 + pb[78];
    float fy = pb[75] * cx0 + pb[76] * cy0 + pb[77] * cz0 + pb[79];
#pragma unroll
    for (int l = 0; l < kL; ++l) {
      float zvl = Zv[l];
      fx = fmaf(pb[l], zvl, fx);
      fy = fmaf(pb[kL + l], zvl, fy);
    }
    int xq = (int)floorf(fx * 2048.f);
    int yq = (int)floorf(fy * 2048.f);
    fxq[b] = xq;
    fyq[b] = yq;
    int x0 = xq >> 11, y0 = yq >> 11;
    if (act && x0 >= -1 && x0 <= 255 && y0 >= -1 && y0 <= 255) {
      flags |= 1u << b;
      int q0 = y0 >> 4;        // may be -1
      int q1 = (y0 + 1) >> 4;  // 0..16
      if (q0 >= 0) atomicAdd(&s_cnt[b * kNStrip + q0], 1u);
      if (q1 <= 15 && q1 != q0) atomicAdd(&s_cnt[b * kNStrip + q1], 1u);
    }
  }
  __syncthreads();

  // reserve: one concurrent global atomic round, one counter per thread
  {
    unsigned cnt = s_cnt[tid];
    s_base[tid] = cnt ? atomicAdd(&gcnt[tid], cnt) : 0u;
    s_cnt[tid] = 0u;  // reset for slot pass
  }
  __syncthreads();

  // pass 2: slots + writes (no trailing barrier; stores drain at kernel end)
#pragma unroll
  for (int b = 0; b < kB; ++b) {
    if (!((flags >> b) & 1u)) continue;
    int xq = fxq[b], yq = fyq[b];
    int x0 = xq >> 11, y0 = yq >> 11;
    unsigned qwx = (unsigned)(xq & 2047), qwy = (unsigned)(yq & 2047);
    uint2 rec;
    rec.x = (unsigned)(x0 + 1) | ((unsigned)(y0 + 1) << 9) | (qwx << 18) |
            ((qwy & 7u) << 29);
    rec.y = (qwy >> 3) | (qv << 8);
    int q0 = y0 >> 4;
    int q1 = (y0 + 1) >> 4;
    if (q0 >= 0) {
      int c = b * kNStrip + q0;
      unsigned sl = atomicAdd(&s_cnt[c], 1u);
      unsigned idx = s_base[c] + sl;
      if (idx < (unsigned)kCAP) arena[(size_t)c * kCAP + idx] = rec;
    }
    if (q1 <= 15 && q1 != q0) {
      int c = b * kNStrip + q1;
      unsigned sl = atomicAdd(&s_cnt[c], 1u);
      unsigned idx = s_base[c] + sl;
      if (idx < (unsigned)kCAP) arena[(size_t)c * kCAP + idx] = rec;
    }
  }
}

// ---------------------------------------------------------------------------
// Phase 2: one block per (b, strip): accumulate records into LDS tile with
// native integer atomics (ds_add_u32, fixed point 2^20), flush plain stores.
// ---------------------------------------------------------------------------
__global__ __launch_bounds__(1024) void k_deposit(
    const uint2* __restrict__ arena, const unsigned* __restrict__ gcnt,
    float* __restrict__ img) {
  __shared__ unsigned tile[kStripRows * kS];  // 16KB
  int tid = threadIdx.x;
  int b = blockIdx.x >> 4;
  int q = blockIdx.x & 15;
  for (int i = tid; i < kStripRows * kS; i += 1024) tile[i] = 0u;
  __syncthreads();
  unsigned cnt = gcnt[b * kNStrip + q];
  if (cnt > (unsigned)kCAP) cnt = kCAP;
  const uint2* rec = arena + (size_t)(b * kNStrip + q) * kCAP;
  for (unsigned i = tid; i < cnt; i += 1024) {
    uint2 r = rec[i];
    int x0 = (int)(r.x & 511u) - 1;
    int y0 = (int)((r.x >> 9) & 511u) - 1;
    float wx1 = (float)((r.x >> 18) & 2047u) * (1.f / 2048.f);
    float wy1 = (float)(((r.x >> 29) & 7u) | ((r.y & 255u) << 3)) * (1.f / 2048.f);
    float v = (float)(r.y >> 8) * (1.f / 16777216.f);
    float wx0 = 1.f - wx1, wy0 = 1.f - wy1;
#pragma unroll
    for (int dy = 0; dy < 2; ++dy) {
      int row = y0 + dy;
      if ((row >> 4) != q) continue;  // also rejects row<0 / row>255
      float wv = (dy ? wy1 : wy0) * v;
      int rr = (row & 15) * kS;
      if (x0 >= 0)
        atomicAdd(&tile[rr + x0], (unsigned)(wv * wx0 * kFxScale + 0.5f));
      if (x0 + 1 <= 255)
        atomicAdd(&tile[rr + x0 + 1], (unsigned)(wv * wx1 * kFxScale + 0.5f));
    }
  }
  __syncthreads();
  float* dst = img + (size_t)b * kS * kS + (size_t)q * kStripRows * kS;
  for (int i = tid; i < kStripRows * kS; i += 1024)
    dst[i] = (float)tile[i] * (1.f / kFxScale);
}

// ---------------------------------------------------------------------------
// Fallback: direct-atomic scatter (used only if ws_size is too small)
// ---------------------------------------------------------------------------
__global__ __launch_bounds__(256) void k_scatter(
    const float* __restrict__ proj, const float* __restrict__ Zvol,
    const float* __restrict__ coords, const float* __restrict__ values,
    float* __restrict__ img) {
  int tid = threadIdx.x;
  int n = blockIdx.x * 256 + tid;
  if (n >= kN) return;
  float Zv[kL];
  const float4* zrow = reinterpret_cast<const float4*>(Zvol + (size_t)n * kL);
#pragma unroll
  for (int q = 0; q < kL / 4; ++q) {
    float4 f = zrow[q];
    Zv[4 * q + 0] = f.x; Zv[4 * q + 1] = f.y;
    Zv[4 * q + 2] = f.z; Zv[4 * q + 3] = f.w;
  }
  float cx0 = coords[(size_t)n * 3 + 0];
  float cy0 = coords[(size_t)n * 3 + 1];
  float cz0 = coords[(size_t)n * 3 + 2];
  float v = values[n];
  for (int b = 0; b < kB; ++b) {
    const float* pb = proj + b * kProjStride;
    float fx = pb[72] * cx0 + pb[73] * cy0 + pb[74] * cz0 + pb[78];
    float fy = pb[75] * cx0 + pb[76] * cy0 + pb[77] * cz0 + pb[79];
#pragma unroll
    for (int l = 0; l < kL; ++l) {
      float zvl = Zv[l];
      fx = fmaf(pb[l], zvl, fx);
      fy = fmaf(pb[kL + l], zvl, fy);
    }
    float x0f = floorf(fx), y0f = floorf(fy);
    float wx1 = fx - x0f, wy1 = fy - y0f;
    float wx0 = 1.f - wx1, wy0 = 1.f - wy1;
    int x0 = (int)x0f, y0 = (int)y0f;
    float* imb = img + (size_t)b * kS * kS;
#pragma unroll
    for (int dyi = 0; dyi < 2; ++dyi) {
      int yi = y0 + dyi;
      if ((unsigned)yi >= (unsigned)kS) continue;
      float wy = dyi ? wy1 : wy0;
#pragma unroll
      for (int dxi = 0; dxi < 2; ++dxi) {
        int xi = x0 + dxi;
        if ((unsigned)xi >= (unsigned)kS) continue;
        float wx = dxi ? wx1 : wx0;
        unsafeAtomicAdd(imb + yi * kS + xi, wy * wx * v);
      }
    }
  }
}

// ---------------------------------------------------------------------------
// Atoms fallback (ws-small path) + fused bond/angle
// ---------------------------------------------------------------------------
__global__ __launch_bounds__(256) void k_atoms(
    const float* __restrict__ zx, const float* __restrict__ zy,
    const float* __restrict__ zz, const float* __restrict__ Za,
    const float* __restrict__ ac, float* __restrict__ atoms) {
  int i = blockIdx.x * 256 + threadIdx.x;
  if (i >= kNA) return;
  float Zv[kL];
  const float4* zrow = reinterpret_cast<const float4*>(Za + (size_t)i * kL);
#pragma unroll
  for (int q = 0; q < kL / 4; ++q) {
    float4 f = zrow[q];
    Zv[4 * q + 0] = f.x; Zv[4 * q + 1] = f.y;
    Zv[4 * q + 2] = f.z; Zv[4 * q + 3] = f.w;
  }
  float ax = ac[(size_t)i * 3 + 0];
  float ay = ac[(size_t)i * 3 + 1];
  float az = ac[(size_t)i * 3 + 2];
  for (int b = 0; b < kB; ++b) {
    float dx = 0.f, dy = 0.f, dz = 0.f;
#pragma unroll
    for (int l = 0; l < kL; ++l) {
      float zvl = Zv[l];
      dx = fmaf(zx[b * kL + l], zvl, dx);
      dy = fmaf(zy[b * kL + l], zvl, dy);
      dz = fmaf(zz[b * kL + l], zvl, dz);
    }
    size_t o = ((size_t)b * kNA + i) * 3;
    atoms[o + 0] = ax + dx;
    atoms[o + 1] = ay + dy;
    atoms[o + 2] = az + dz;
  }
}

__global__ __launch_bounds__(256) void k_bondangle(
    const float* __restrict__ atoms, const int* __restrict__ bidx,
    const int* __restrict__ aidx, float* __restrict__ out_bond,
    float* __restrict__ out_angle) {
  int t = blockIdx.x * 256 + threadIdx.x;
  if (t < kB * kNB) {
    int j = t % kNB;
    int b = t / kNB;
    int i0 = bidx[(size_t)j * 2 + 0];
    int i1 = bidx[(size_t)j * 2 + 1];
    const float* base = atoms + (size_t)b * kNA * 3;
    const float* p0 = base + (size_t)i0 * 3;
    const float* p1 = base + (size_t)i1 * 3;
    float dx = p0[0] - p1[0];
    float dy = p0[1] - p1[1];
    float dz = p0[2] - p1[2];
    out_bond[t] = sqrtf(dx * dx + dy * dy + dz * dz + 1e-12f);
    return;
  }
  t -= kB * kNB;
  if (t >= kB * kNC) return;
  int j = t % kNC;
  int b = t / kNC;
  int i0 = aidx[(size_t)j * 3 + 0];
  int i1 = aidx[(size_t)j * 3 + 1];
  int i2 = aidx[(size_t)j * 3 + 2];
  const float* base = atoms + (size_t)b * kNA * 3;
  const float* p0 = base + (size_t)i0 * 3;
  const float* p1 = base + (size_t)i1 * 3;
  const float* p2 = base + (size_t)i2 * 3;
  float ux = p0[0] - p1[0], uy = p0[1] - p1[1], uz = p0[2] - p1[2];
  float vx = p2[0] - p1[0], vy = p2[1] - p1[1], vz = p2[2] - p1[2];
  float uv = ux * vx + uy * vy + uz * vz;
  float uu = ux * ux + uy * uy + uz * uz;
  float vv = vx * vx + vy * vy + vz * vz;
  float c = uv / (sqrtf(uu * vv) + 1e-6f);
  c = fminf(0.999f, fmaxf(-0.999f, c));
  out_angle[t] = acosf(c);
}

// ---------------------------------------------------------------------------
// 256-point radix-2 DIT FFT, TWO LINES per 256-thread block.
// line l = tid>>7, lane t = tid&127. Every thread does 1 butterfly/stage.
// sign=-1 forward, +1 inverse (unnormalized).
// ---------------------------------------------------------------------------
__device__ __forceinline__ void fft256x2_lds(float (*re)[kS], float (*im)[kS],
                                             int l, int t, float sign) {
  unsigned r0 = __brev((unsigned)t) >> 24;
  float a0 = re[l][t], b0 = im[l][t];
  float a1 = re[l][t + 128], b1 = im[l][t + 128];
  __syncthreads();
  re[l][r0] = a0;
  im[l][r0] = b0;
  re[l][r0 + 1] = a1;
  im[l][r0 + 1] = b1;
  __syncthreads();
#pragma unroll
  for (int s = 1; s <= 8; ++s) {
    int half = 1 << (s - 1);
    int k = t & (half - 1);
    int i0 = ((t >> (s - 1)) << s) | k;
    int i1 = i0 + half;
    float ang = sign * (3.14159265358979f * (float)k / (float)half);
    float sn, cs;
    __sincosf(ang, &sn, &cs);
    float xr = re[l][i1], xi = im[l][i1];
    float tr = cs * xr - sn * xi;
    float ti = cs * xi + sn * xr;
    float ur = re[l][i0], ui = im[l][i0];
    re[l][i0] = ur + tr;
    im[l][i0] = ui + ti;
    re[l][i1] = ur - tr;
    im[l][i1] = ui - ti;
    __syncthreads();
  }
}

// Pass 1 (fused 5x5 Gaussian conv + forward row FFT), 2 lines (y, y+1)/block.
__global__ __launch_bounds__(256) void k_conv_fft_rows(
    const float* __restrict__ img, float* __restrict__ outRe,
    float* __restrict__ outIm) {
  __shared__ float rows[6][260];
  __shared__ float re[2][kS], im[2][kS];
  int tid = threadIdx.x;
  int blk = blockIdx.x;           // b*128 + y/2
  int b = blk >> 7, y0 = (blk & 127) * 2;
  const float* imb = img + (size_t)b * kS * kS;
#pragma unroll
  for (int r = 0; r < 6; ++r) {
    int yy = y0 + r - 2;
    rows[r][tid + 2] = ((unsigned)yy < (unsigned)kS) ? imb[yy * kS + tid] : 0.f;
  }
  if (tid < 2) {
#pragma unroll
    for (int r = 0; r < 6; ++r) {
      rows[r][tid] = 0.f;
      rows[r][258 + tid] = 0.f;
    }
  }
  __syncthreads();
  const float wt[5] = {0.05448868454f, 0.24420134723f, 0.40261993646f,
                       0.24420134723f, 0.05448868454f};
  int l = tid >> 7, t = tid & 127;
#pragma unroll
  for (int e = 0; e < 2; ++e) {
    int col = t + e * 128;
    float acc = 0.f;
#pragma unroll
    for (int r = 0; r < 5; ++r) {
      float rs = 0.f;
#pragma unroll
      for (int c = 0; c < 5; ++c) rs = fmaf(wt[c], rows[l + r][col + c], rs);
      acc = fmaf(wt[r], rs, acc);
    }
    re[l][col] = acc;
    im[l][col] = 0.f;
  }
  fft256x2_lds(re, im, l, t, -1.f);
  size_t ob = (size_t)b * kS * kS + (y0 + l);
  outRe[ob + (size_t)t * kS] = re[l][t];
  outIm[ob + (size_t)t * kS] = im[l][t];
  outRe[ob + (size_t)(t + 128) * kS] = re[l][t + 128];
  outIm[ob + (size_t)(t + 128) * kS] = im[l][t + 128];
}

// Pass 2: forward FFT over y, multiply by ctfT (coalesced), inverse FFT.
// No barrier needed between the multiply and the inverse FFT: each thread
// multiplies exactly the elements it alone re-reads at the start of
// fft256x2_lds, whose first cross-thread write is behind its own barrier.
__global__ __launch_bounds__(256) void k_fft_cols(
    const float* __restrict__ inRe, const float* __restrict__ inIm,
    const float* __restrict__ ctfT, float* __restrict__ outRe,
    float* __restrict__ outIm) {
  __shared__ float re[2][kS], im[2][kS];
  int tid = threadIdx.x;
  int blk = blockIdx.x;           // b*128 + kx/2
  int b = blk >> 7, kx0 = (blk & 127) * 2;
  int l = tid >> 7, t = tid & 127;
  size_t base = ((size_t)b * kS + kx0 + l) * kS;
  re[l][t] = inRe[base + t];
  im[l][t] = inIm[base + t];
  re[l][t + 128] = inRe[base + t + 128];
  im[l][t + 128] = inIm[base + t + 128];
  fft256x2_lds(re, im, l, t, -1.f);
  float c0 = ctfT[base + t];
  float c1 = ctfT[base + t + 128];
  re[l][t] *= c0;
  im[l][t] *= c0;
  re[l][t + 128] *= c1;
  im[l][t + 128] *= c1;
  fft256x2_lds(re, im, l, t, 1.f);
  size_t ob = (size_t)b * kS * kS + (kx0 + l);
  outRe[ob + (size_t)t * kS] = re[l][t] * (1.f / 256.f);
  outIm[ob + (size_t)t * kS] = im[l][t] * (1.f / 256.f);
  outRe[ob + (size_t)(t + 128) * kS] = re[l][t + 128] * (1.f / 256.f);
  outIm[ob + (size_t)(t + 128) * kS] = im[l][t + 128] * (1.f / 256.f);
}

// Pass 3: inverse FFT over x, real part -> out image. 2 y-lines per block.
__global__ __launch_bounds__(256) void k_fft_rows_inv(
    const float* __restrict__ inRe, const float* __restrict__ inIm,
    float* __restrict__ out) {
  __shared__ float re[2][kS], im[2][kS];
  int tid = threadIdx.x;
  int blk = blockIdx.x;           // b*128 + y/2
  int b = blk >> 7, y0 = (blk & 127) * 2;
  int l = tid >> 7, t = tid & 127;
  size_t base = ((size_t)b * kS + y0 + l) * kS;
  re[l][t] = inRe[base + t];
  im[l][t] = inIm[base + t];
  re[l][t + 128] = inRe[base + t + 128];
  im[l][t + 128] = inIm[base + t + 128];
  fft256x2_lds(re, im, l, t, 1.f);
  out[base + t] = re[l][t] * (1.f / 256.f);
  out[base + t + 128] = re[l][t + 128] * (1.f / 256.f);
}

// ---------------------------------------------------------------------------
extern "C" void kernel_launch(void* const* d_in, const int* in_sizes, int n_in,
                              void* d_out, int out_size, void* d_ws,
                              size_t ws_size, hipStream_t stream) {
  const float* zx     = (const float*)d_in[0];
  const float* zy     = (const float*)d_in[1];
  const float* zz     = (const float*)d_in[2];
  const float* de     = (const float*)d_in[3];
  const float* dsh    = (const float*)d_in[4];
  const float* Zvol   = (const float*)d_in[5];
  const float* Za     = (const float*)d_in[6];
  const float* coords = (const float*)d_in[7];
  const float* values = (const float*)d_in[8];
  const float* ac     = (const float*)d_in[9];
  const float* ctf    = (const float*)d_in[10];
  const int*   bidx   = (const int*)d_in[11];
  const int*   aidx   = (const int*)d_in[12];

  float* ws    = (float*)d_ws;
  float* imgA  = ws;                           // scatter target; later dIm
  float* imgB  = ws + kImgElems;               // later dRe
  float* cRe   = ws + 2 * (size_t)kImgElems;
  float* cIm   = ws + 3 * (size_t)kImgElems;
  float* atoms = ws + 4 * (size_t)kImgElems;   // B*NA*3 floats
  unsigned* gcnt = (unsigned*)(atoms + (size_t)kB * kNA * 3);  // 256 counters
  float* proj = (float*)(gcnt + 256);          // kB*kProjStride floats
  uint2* arena = (uint2*)(proj + kB * kProjStride);
  size_t fixedBytes =
      (size_t)(4 * (size_t)kImgElems + (size_t)kB * kNA * 3 + 256 +
               kB * kProjStride) * 4;

  float* dRe = imgB;
  float* dIm = imgA;
  float* out_img   = (float*)d_out;
  float* out_bond  = out_img + kImgElems;
  float* out_angle = out_bond + (size_t)kB * kNB;
  // ctfT scratch lives in out_img: written by k_ctfT, read by k_fft_cols,
  // then overwritten by k_fft_rows_inv. Lifetimes do not overlap per-kernel.
  float* ctfT = out_img;

  size_t avail = (ws_size > fixedBytes) ? (ws_size - fixedBytes) : 0;
  bool full = ((size_t)kB * kNStrip * kCAP * sizeof(uint2)) <= avail;

  {
    dim3 tg(8, 8, kB);
    k_ctfT<<<tg, 256, 0, stream>>>(ctf, ctfT, zx, zy, zz, de, dsh, proj);
  }

  if (full) {
    hipMemsetAsync(gcnt, 0, 256 * sizeof(unsigned), stream);
    k_project<<<kProjBlocks + kAtomBlocks, kPB, 0, stream>>>(
        proj, Zvol, coords, values, arena, gcnt, zx, zy, zz, Za, ac, atoms);
    k_deposit<<<kB * kNStrip, 1024, 0, stream>>>(arena, gcnt, imgA);
  } else {
    hipMemsetAsync(imgA, 0, (size_t)kImgElems * sizeof(float), stream);
    k_scatter<<<(kN + 255) / 256, 256, 0, stream>>>(proj, Zvol, coords, values,
                                                    imgA);
    k_atoms<<<(kNA + 255) / 256, 256, 0, stream>>>(zx, zy, zz, Za, ac, atoms);
  }

  k_conv_fft_rows<<<kB * kS / 2, 256, 0, stream>>>(imgA, cRe, cIm);
  k_fft_cols<<<kB * kS / 2, 256, 0, stream>>>(cRe, cIm, ctfT, dRe, dIm);
  k_fft_rows_inv<<<kB * kS / 2, 256, 0, stream>>>(dRe, dIm, out_img);

  k_bondangle<<<(kB * (kNB + kNC) + 255) / 256, 256, 0, stream>>>(
      atoms, bidx, aidx, out_bond, out_angle);
}

// Round 19
// 157.659 us; speedup vs baseline: 1.1951x; 1.0195x over previous
//
#include <hip/hip_runtime.h>
#include <math.h>

// Problem constants (match reference)
constexpr int kS  = 256;
constexpr int kB  = 16;
constexpr int kL  = 36;
constexpr int kN  = 400000;
constexpr int kNA = 50000;
constexpr int kNB = 50000;
constexpr int kNC = 50000;

constexpr int kImgElems = kB * kS * kS;  // 1,048,576
constexpr int kNStrip = 16;              // strips per image (16 rows each)
constexpr int kStripRows = 16;
constexpr int kCAP = 32768;              // records per bucket (expected max ~28K)
constexpr float kFxScale = 1048576.f;    // 2^20 fixed-point scale for deposit
constexpr int kProjStride = 80;          // floats per b in proj table
constexpr int kPB = 256;                 // threads (points) per project block
constexpr int kProjBlocks = (kN + kPB - 1) / kPB;   // 1563
constexpr int kAtomBlocks = (kNA + kPB - 1) / kPB;  // 196
constexpr int kDepBlocks = kB * kNStrip;            // 256 deposit blocks
constexpr int kBATotal = kB * (kNB + kNC);          // 1,600,000 bond+angle items
constexpr int kBABlocks = (kBATotal + 1023) / 1024; // 1563

// ---------------------------------------------------------------------------
// ctf transpose (+ fused prep in block 0): ctfT[b][x][y] = ctf[b][y][x]
// ---------------------------------------------------------------------------
__global__ __launch_bounds__(256) void k_ctfT(
    const float* __restrict__ ctf, float* __restrict__ ctfT,
    const float* __restrict__ zx, const float* __restrict__ zy,
    const float* __restrict__ zz, const float* __restrict__ de,
    const float* __restrict__ dsh, float* __restrict__ proj) {
  __shared__ float tile[32][33];
  int b = blockIdx.z;
  int x0 = blockIdx.x * 32, y0 = blockIdx.y * 32;
  int tx = threadIdx.x & 31, ty4 = threadIdx.x >> 5;  // 32 x 8
  const float* src = ctf + (size_t)b * kS * kS;
  float* dst = ctfT + (size_t)b * kS * kS;
#pragma unroll
  for (int r = 0; r < 4; ++r) {
    int y = y0 + ty4 + r * 8;
    tile[ty4 + r * 8][tx] = src[y * kS + x0 + tx];
  }
  __syncthreads();
#pragma unroll
  for (int r = 0; r < 4; ++r) {
    int x = x0 + ty4 + r * 8;
    dst[(size_t)x * kS + y0 + tx] = tile[tx][ty4 + r * 8];
  }
  // fused prep: per-b combined projection weights (block 0 only)
  if (b == 0 && blockIdx.x == 0 && blockIdx.y == 0 && threadIdx.x < kB) {
    int pbi = threadIdx.x;
    float a = de[pbi * 3 + 0], bb = de[pbi * 3 + 1], g = de[pbi * 3 + 2];
    float ca, sa, cb, sb, cg, sg;
    sincosf(a, &sa, &ca);
    sincosf(bb, &sb, &cb);
    sincosf(g, &sg, &cg);
    float R0 = cg * cb * ca - sg * sa;
    float R1 = cg * cb * sa + sg * ca;
    float R2 = -cg * sb;
    float R3 = -sg * cb * ca - cg * sa;
    float R4 = -sg * cb * sa + cg * ca;
    float R5 = sg * sb;
    float* p = proj + pbi * kProjStride;
    for (int l = 0; l < kL; ++l) {
      float x = zx[pbi * kL + l], y = zy[pbi * kL + l], z = zz[pbi * kL + l];
      p[l]      = R0 * x + R1 * y + R2 * z;
      p[kL + l] = R3 * x + R4 * y + R5 * z;
    }
    p[72] = R0; p[73] = R1; p[74] = R2;
    p[75] = R3; p[76] = R4; p[77] = R5;
    p[78] = dsh[pbi * 2 + 0] + 128.0f;
    p[79] = dsh[pbi * 2 + 1] + 128.0f;
  }
}

// ---------------------------------------------------------------------------
// Phase 1: project + fused atoms. ATOMS BLOCKS FIRST (round-18 verified win:
// 65-69us; atoms co-run with the project wave instead of draining as a tail).
// Project path: round-15 verified form (256 thr/block, 1 point/thread,
// all 16 b's, VGPR 64, no spill).
// Record (8B): x0+1:9 | y0+1:9 | qwx:11 | qwy:11 | qv:24
// ---------------------------------------------------------------------------
__global__ __launch_bounds__(kPB, 2) void k_project(
    const float* __restrict__ proj, const float* __restrict__ Zvol,
    const float* __restrict__ coords, const float* __restrict__ values,
    uint2* __restrict__ arena, unsigned* __restrict__ gcnt,
    const float* __restrict__ zx, const float* __restrict__ zy,
    const float* __restrict__ zz, const float* __restrict__ Za,
    const float* __restrict__ ac, float* __restrict__ atoms) {
  int tid = threadIdx.x;

  if (blockIdx.x < kAtomBlocks) {
    // ------------------ fused k_atoms path (runs FIRST) ------------------
    int i = blockIdx.x * kPB + tid;
    if (i >= kNA) return;
    float Zv[kL];
    const float4* zrow = reinterpret_cast<const float4*>(Za + (size_t)i * kL);
#pragma unroll
    for (int q = 0; q < kL / 4; ++q) {
      float4 f = zrow[q];
      Zv[4 * q + 0] = f.x; Zv[4 * q + 1] = f.y;
      Zv[4 * q + 2] = f.z; Zv[4 * q + 3] = f.w;
    }
    float ax = ac[(size_t)i * 3 + 0];
    float ay = ac[(size_t)i * 3 + 1];
    float az = ac[(size_t)i * 3 + 2];
    for (int b = 0; b < kB; ++b) {
      float dx = 0.f, dy = 0.f, dz = 0.f;
#pragma unroll
      for (int l = 0; l < kL; ++l) {
        float zvl = Zv[l];
        dx = fmaf(zx[b * kL + l], zvl, dx);
        dy = fmaf(zy[b * kL + l], zvl, dy);
        dz = fmaf(zz[b * kL + l], zvl, dz);
      }
      size_t o = ((size_t)b * kNA + i) * 3;
      atoms[o + 0] = ax + dx;
      atoms[o + 1] = ay + dy;
      atoms[o + 2] = az + dz;
    }
    return;
  }

  // ------------------ project path (round-15 verified form) -----------------
  __shared__ unsigned s_cnt[kB * kNStrip];  // 256 counters
  __shared__ unsigned s_base[kB * kNStrip];
  s_cnt[tid] = 0u;

  int n = (blockIdx.x - kAtomBlocks) * kPB + tid;
  bool act = n < kN;
  float Zv[kL];
  float cx0 = 0.f, cy0 = 0.f, cz0 = 0.f, v = 0.f;
  if (act) {
    const float4* zrow = reinterpret_cast<const float4*>(Zvol + (size_t)n * kL);
#pragma unroll
    for (int q = 0; q < kL / 4; ++q) {
      float4 f = zrow[q];
      Zv[4 * q + 0] = f.x; Zv[4 * q + 1] = f.y;
      Zv[4 * q + 2] = f.z; Zv[4 * q + 3] = f.w;
    }
    cx0 = coords[(size_t)n * 3 + 0];
    cy0 = coords[(size_t)n * 3 + 1];
    cz0 = coords[(size_t)n * 3 + 2];
    v = values[n];
  }
  unsigned qv = (unsigned)(v * 16777216.f);
  if (qv > 16777215u) qv = 16777215u;
  __syncthreads();  // counters zeroed

  int fxq[kB], fyq[kB];
  unsigned flags = 0;

  // pass 1: compute + count
#pragma unroll
  for (int b = 0; b < kB; ++b) {
    const float* pb = proj + b * kProjStride;  // uniform -> s_loads
    float fx = pb[72] * cx0 + pb[73] * cy0 + pb[74] * cz0 + pb[78];
    float fy = pb[75] * cx0 + pb[76] * cy0 + pb[77] * cz0 + pb[79];
#pragma unroll
    for (int l = 0; l < kL; ++l) {
      float zvl = Zv[l];
      fx = fmaf(pb[l], zvl, fx);
      fy = fmaf(pb[kL + l], zvl, fy);
    }
    int xq = (int)floorf(fx * 2048.f);
    int yq = (int)floorf(fy * 2048.f);
    fxq[b] = xq;
    fyq[b] = yq;
    int x0 = xq >> 11, y0 = yq >> 11;
    if (act && x0 >= -1 && x0 <= 255 && y0 >= -1 && y0 <= 255) {
      flags |= 1u << b;
      int q0 = y0 >> 4;        // may be -1
      int q1 = (y0 + 1) >> 4;  // 0..16
      if (q0 >= 0) atomicAdd(&s_cnt[b * kNStrip + q0], 1u);
      if (q1 <= 15 && q1 != q0) atomicAdd(&s_cnt[b * kNStrip + q1], 1u);
    }
  }
  __syncthreads();

  // reserve: one concurrent global atomic round, one counter per thread
  {
    unsigned cnt = s_cnt[tid];
    s_base[tid] = cnt ? atomicAdd(&gcnt[tid], cnt) : 0u;
    s_cnt[tid] = 0u;  // reset for slot pass
  }
  __syncthreads();

  // pass 2: slots + writes (no trailing barrier; stores drain at kernel end)
#pragma unroll
  for (int b = 0; b < kB; ++b) {
    if (!((flags >> b) & 1u)) continue;
    int xq = fxq[b], yq = fyq[b];
    int x0 = xq >> 11, y0 = yq >> 11;
    unsigned qwx = (unsigned)(xq & 2047), qwy = (unsigned)(yq & 2047);
    uint2 rec;
    rec.x = (unsigned)(x0 + 1) | ((unsigned)(y0 + 1) << 9) | (qwx << 18) |
            ((qwy & 7u) << 29);
    rec.y = (qwy >> 3) | (qv << 8);
    int q0 = y0 >> 4;
    int q1 = (y0 + 1) >> 4;
    if (q0 >= 0) {
      int c = b * kNStrip + q0;
      unsigned sl = atomicAdd(&s_cnt[c], 1u);
      unsigned idx = s_base[c] + sl;
      if (idx < (unsigned)kCAP) arena[(size_t)c * kCAP + idx] = rec;
    }
    if (q1 <= 15 && q1 != q0) {
      int c = b * kNStrip + q1;
      unsigned sl = atomicAdd(&s_cnt[c], 1u);
      unsigned idx = s_base[c] + sl;
      if (idx < (unsigned)kCAP) arena[(size_t)c * kCAP + idx] = rec;
    }
  }
}

// ---------------------------------------------------------------------------
// Phase 2 (fused): blocks 0..255 deposit (launched first: long-pole per-block
// work starts on all CUs immediately); blocks 256+ do bond/angle at 1024
// threads, filling CU slots the 1-block/CU deposit phase leaves idle.
// bondangle depends only on atoms (complete after k_project).
// ---------------------------------------------------------------------------
__global__ __launch_bounds__(1024) void k_deposit_ba(
    const uint2* __restrict__ arena, const unsigned* __restrict__ gcnt,
    float* __restrict__ img, const float* __restrict__ atoms,
    const int* __restrict__ bidx, const int* __restrict__ aidx,
    float* __restrict__ out_bond, float* __restrict__ out_angle) {
  int tid = threadIdx.x;

  if (blockIdx.x >= kDepBlocks) {
    // ------------------ fused bond/angle path ------------------
    int t = (blockIdx.x - kDepBlocks) * 1024 + tid;
    if (t < kB * kNB) {
      int j = t % kNB;
      int b = t / kNB;
      int i0 = bidx[(size_t)j * 2 + 0];
      int i1 = bidx[(size_t)j * 2 + 1];
      const float* base = atoms + (size_t)b * kNA * 3;
      const float* p0 = base + (size_t)i0 * 3;
      const float* p1 = base + (size_t)i1 * 3;
      float dx = p0[0] - p1[0];
      float dy = p0[1] - p1[1];
      float dz = p0[2] - p1[2];
      out_bond[t] = sqrtf(dx * dx + dy * dy + dz * dz + 1e-12f);
      return;
    }
    t -= kB * kNB;
    if (t >= kB * kNC) return;
    int j = t % kNC;
    int b = t / kNC;
    int i0 = aidx[(size_t)j * 3 + 0];
    int i1 = aidx[(size_t)j * 3 + 1];
    int i2 = aidx[(size_t)j * 3 + 2];
    const float* base = atoms + (size_t)b * kNA * 3;
    const float* p0 = base + (size_t)i0 * 3;
    const float* p1 = base + (size_t)i1 * 3;
    const float* p2 = base + (size_t)i2 * 3;
    float ux = p0[0] - p1[0], uy = p0[1] - p1[1], uz = p0[2] - p1[2];
    float vx = p2[0] - p1[0], vy = p2[1] - p1[1], vz = p2[2] - p1[2];
    float uv = ux * vx + uy * vy + uz * vz;
    float uu = ux * ux + uy * uy + uz * uz;
    float vv = vx * vx + vy * vy + vz * vz;
    float c = uv / (sqrtf(uu * vv) + 1e-6f);
    c = fminf(0.999f, fmaxf(-0.999f, c));
    out_angle[t] = acosf(c);
    return;
  }

  // ------------------ deposit path ------------------
  __shared__ unsigned tile[kStripRows * kS];  // 16KB
  int b = blockIdx.x >> 4;
  int q = blockIdx.x & 15;
  for (int i = tid; i < kStripRows * kS; i += 1024) tile[i] = 0u;
  __syncthreads();
  unsigned cnt = gcnt[b * kNStrip + q];
  if (cnt > (unsigned)kCAP) cnt = kCAP;
  const uint2* rec = arena + (size_t)(b * kNStrip + q) * kCAP;
  for (unsigned i = tid; i < cnt; i += 1024) {
    uint2 r = rec[i];
    int x0 = (int)(r.x & 511u) - 1;
    int y0 = (int)((r.x >> 9) & 511u) - 1;
    float wx1 = (float)((r.x >> 18) & 2047u) * (1.f / 2048.f);
    float wy1 = (float)(((r.x >> 29) & 7u) | ((r.y & 255u) << 3)) * (1.f / 2048.f);
    float v = (float)(r.y >> 8) * (1.f / 16777216.f);
    float wx0 = 1.f - wx1, wy0 = 1.f - wy1;
#pragma unroll
    for (int dy = 0; dy < 2; ++dy) {
      int row = y0 + dy;
      if ((row >> 4) != q) continue;  // also rejects row<0 / row>255
      float wv = (dy ? wy1 : wy0) * v;
      int rr = (row & 15) * kS;
      if (x0 >= 0)
        atomicAdd(&tile[rr + x0], (unsigned)(wv * wx0 * kFxScale + 0.5f));
      if (x0 + 1 <= 255)
        atomicAdd(&tile[rr + x0 + 1], (unsigned)(wv * wx1 * kFxScale + 0.5f));
    }
  }
  __syncthreads();
  float* dst = img + (size_t)b * kS * kS + (size_t)q * kStripRows * kS;
  for (int i = tid; i < kStripRows * kS; i += 1024)
    dst[i] = (float)tile[i] * (1.f / kFxScale);
}

// ---------------------------------------------------------------------------
// Fallback: direct-atomic scatter (used only if ws_size is too small)
// ---------------------------------------------------------------------------
__global__ __launch_bounds__(256) void k_scatter(
    const float* __restrict__ proj, const float* __restrict__ Zvol,
    const float* __restrict__ coords, const float* __restrict__ values,
    float* __restrict__ img) {
  int tid = threadIdx.x;
  int n = blockIdx.x * 256 + tid;
  if (n >= kN) return;
  float Zv[kL];
  const float4* zrow = reinterpret_cast<const float4*>(Zvol + (size_t)n * kL);
#pragma unroll
  for (int q = 0; q < kL / 4; ++q) {
    float4 f = zrow[q];
    Zv[4 * q + 0] = f.x; Zv[4 * q + 1] = f.y;
    Zv[4 * q + 2] = f.z; Zv[4 * q + 3] = f.w;
  }
  float cx0 = coords[(size_t)n * 3 + 0];
  float cy0 = coords[(size_t)n * 3 + 1];
  float cz0 = coords[(size_t)n * 3 + 2];
  float v = values[n];
  for (int b = 0; b < kB; ++b) {
    const float* pb = proj + b * kProjStride;
    float fx = pb[72] * cx0 + pb[73] * cy0 + pb[74] * cz0 + pb[78];
    float fy = pb[75] * cx0 + pb[76] * cy0 + pb[77] * cz0 + pb[79];
#pragma unroll
    for (int l = 0; l < kL; ++l) {
      float zvl = Zv[l];
      fx = fmaf(pb[l], zvl, fx);
      fy = fmaf(pb[kL + l], zvl, fy);
    }
    float x0f = floorf(fx), y0f = floorf(fy);
    float wx1 = fx - x0f, wy1 = fy - y0f;
    float wx0 = 1.f - wx1, wy0 = 1.f - wy1;
    int x0 = (int)x0f, y0 = (int)y0f;
    float* imb = img + (size_t)b * kS * kS;
#pragma unroll
    for (int dyi = 0; dyi < 2; ++dyi) {
      int yi = y0 + dyi;
      if ((unsigned)yi >= (unsigned)kS) continue;
      float wy = dyi ? wy1 : wy0;
#pragma unroll
      for (int dxi = 0; dxi < 2; ++dxi) {
        int xi = x0 + dxi;
        if ((unsigned)xi >= (unsigned)kS) continue;
        float wx = dxi ? wx1 : wx0;
        unsafeAtomicAdd(imb + yi * kS + xi, wy * wx * v);
      }
    }
  }
}

// ---------------------------------------------------------------------------
// Atoms fallback (ws-small path) + standalone bond/angle (fallback path)
// ---------------------------------------------------------------------------
__global__ __launch_bounds__(256) void k_atoms(
    const float* __restrict__ zx, const float* __restrict__ zy,
    const float* __restrict__ zz, const float* __restrict__ Za,
    const float* __restrict__ ac, float* __restrict__ atoms) {
  int i = blockIdx.x * 256 + threadIdx.x;
  if (i >= kNA) return;
  float Zv[kL];
  const float4* zrow = reinterpret_cast<const float4*>(Za + (size_t)i * kL);
#pragma unroll
  for (int q = 0; q < kL / 4; ++q) {
    float4 f = zrow[q];
    Zv[4 * q + 0] = f.x; Zv[4 * q + 1] = f.y;
    Zv[4 * q + 2] = f.z; Zv[4 * q + 3] = f.w;
  }
  float ax = ac[(size_t)i * 3 + 0];
  float ay = ac[(size_t)i * 3 + 1];
  float az = ac[(size_t)i * 3 + 2];
  for (int b = 0; b < kB; ++b) {
    float dx = 0.f, dy = 0.f, dz = 0.f;
#pragma unroll
    for (int l = 0; l < kL; ++l) {
      float zvl = Zv[l];
      dx = fmaf(zx[b * kL + l], zvl, dx);
      dy = fmaf(zy[b * kL + l], zvl, dy);
      dz = fmaf(zz[b * kL + l], zvl, dz);
    }
    size_t o = ((size_t)b * kNA + i) * 3;
    atoms[o + 0] = ax + dx;
    atoms[o + 1] = ay + dy;
    atoms[o + 2] = az + dz;
  }
}

__global__ __launch_bounds__(256) void k_bondangle(
    const float* __restrict__ atoms, const int* __restrict__ bidx,
    const int* __restrict__ aidx, float* __restrict__ out_bond,
    float* __restrict__ out_angle) {
  int t = blockIdx.x * 256 + threadIdx.x;
  if (t < kB * kNB) {
    int j = t % kNB;
    int b = t / kNB;
    int i0 = bidx[(size_t)j * 2 + 0];
    int i1 = bidx[(size_t)j * 2 + 1];
    const float* base = atoms + (size_t)b * kNA * 3;
    const float* p0 = base + (size_t)i0 * 3;
    const float* p1 = base + (size_t)i1 * 3;
    float dx = p0[0] - p1[0];
    float dy = p0[1] - p1[1];
    float dz = p0[2] - p1[2];
    out_bond[t] = sqrtf(dx * dx + dy * dy + dz * dz + 1e-12f);
    return;
  }
  t -= kB * kNB;
  if (t >= kB * kNC) return;
  int j = t % kNC;
  int b = t / kNC;
  int i0 = aidx[(size_t)j * 3 + 0];
  int i1 = aidx[(size_t)j * 3 + 1];
  int i2 = aidx[(size_t)j * 3 + 2];
  const float* base = atoms + (size_t)b * kNA * 3;
  const float* p0 = base + (size_t)i0 * 3;
  const float* p1 = base + (size_t)i1 * 3;
  const float* p2 = base + (size_t)i2 * 3;
  float ux = p0[0] - p1[0], uy = p0[1] - p1[1], uz = p0[2] - p1[2];
  float vx = p2[0] - p1[0], vy = p2[1] - p1[1], vz = p2[2] - p1[2];
  float uv = ux * vx + uy * vy + uz * vz;
  float uu = ux * ux + uy * uy + uz * uz;
  float vv = vx * vx + vy * vy + vz * vz;
  float c = uv / (sqrtf(uu * vv) + 1e-6f);
  c = fminf(0.999f, fmaxf(-0.999f, c));
  out_angle[t] = acosf(c);
}

// ---------------------------------------------------------------------------
// 256-point radix-2 DIT FFT, TWO LINES per 256-thread block.
// line l = tid>>7, lane t = tid&127. Every thread does 1 butterfly/stage.
// sign=-1 forward, +1 inverse (unnormalized).
// ---------------------------------------------------------------------------
__device__ __forceinline__ void fft256x2_lds(float (*re)[kS], float (*im)[kS],
                                             int l, int t, float sign) {
  unsigned r0 = __brev((unsigned)t) >> 24;
  float a0 = re[l][t], b0 = im[l][t];
  float a1 = re[l][t + 128], b1 = im[l][t + 128];
  __syncthreads();
  re[l][r0] = a0;
  im[l][r0] = b0;
  re[l][r0 + 1] = a1;
  im[l][r0 + 1] = b1;
  __syncthreads();
#pragma unroll
  for (int s = 1; s <= 8; ++s) {
    int half = 1 << (s - 1);
    int k = t & (half - 1);
    int i0 = ((t >> (s - 1)) << s) | k;
    int i1 = i0 + half;
    float ang = sign * (3.14159265358979f * (float)k / (float)half);
    float sn, cs;
    __sincosf(ang, &sn, &cs);
    float xr = re[l][i1], xi = im[l][i1];
    float tr = cs * xr - sn * xi;
    float ti = cs * xi + sn * xr;
    float ur = re[l][i0], ui = im[l][i0];
    re[l][i0] = ur + tr;
    im[l][i0] = ui + ti;
    re[l][i1] = ur - tr;
    im[l][i1] = ui - ti;
    __syncthreads();
  }
}

// Pass 1 (fused 5x5 Gaussian conv + forward row FFT), 2 lines (y, y+1)/block.
__global__ __launch_bounds__(256) void k_conv_fft_rows(
    const float* __restrict__ img, float* __restrict__ outRe,
    float* __restrict__ outIm) {
  __shared__ float rows[6][260];
  __shared__ float re[2][kS], im[2][kS];
  int tid = threadIdx.x;
  int blk = blockIdx.x;           // b*128 + y/2
  int b = blk >> 7, y0 = (blk & 127) * 2;
  const float* imb = img + (size_t)b * kS * kS;
#pragma unroll
  for (int r = 0; r < 6; ++r) {
    int yy = y0 + r - 2;
    rows[r][tid + 2] = ((unsigned)yy < (unsigned)kS) ? imb[yy * kS + tid] : 0.f;
  }
  if (tid < 2) {
#pragma unroll
    for (int r = 0; r < 6; ++r) {
      rows[r][tid] = 0.f;
      rows[r][258 + tid] = 0.f;
    }
  }
  __syncthreads();
  const float wt[5] = {0.05448868454f, 0.24420134723f, 0.40261993646f,
                       0.24420134723f, 0.05448868454f};
  int l = tid >> 7, t = tid & 127;
#pragma unroll
  for (int e = 0; e < 2; ++e) {
    int col = t + e * 128;
    float acc = 0.f;
#pragma unroll
    for (int r = 0; r < 5; ++r) {
      float rs = 0.f;
#pragma unroll
      for (int c = 0; c < 5; ++c) rs = fmaf(wt[c], rows[l + r][col + c], rs);
      acc = fmaf(wt[r], rs, acc);
    }
    re[l][col] = acc;
    im[l][col] = 0.f;
  }
  fft256x2_lds(re, im, l, t, -1.f);
  size_t ob = (size_t)b * kS * kS + (y0 + l);
  outRe[ob + (size_t)t * kS] = re[l][t];
  outIm[ob + (size_t)t * kS] = im[l][t];
  outRe[ob + (size_t)(t + 128) * kS] = re[l][t + 128];
  outIm[ob + (size_t)(t + 128) * kS] = im[l][t + 128];
}

// Pass 2: forward FFT over y, multiply by ctfT (coalesced), inverse FFT.
__global__ __launch_bounds__(256) void k_fft_cols(
    const float* __restrict__ inRe, const float* __restrict__ inIm,
    const float* __restrict__ ctfT, float* __restrict__ outRe,
    float* __restrict__ outIm) {
  __shared__ float re[2][kS], im[2][kS];
  int tid = threadIdx.x;
  int blk = blockIdx.x;           // b*128 + kx/2
  int b = blk >> 7, kx0 = (blk & 127) * 2;
  int l = tid >> 7, t = tid & 127;
  size_t base = ((size_t)b * kS + kx0 + l) * kS;
  re[l][t] = inRe[base + t];
  im[l][t] = inIm[base + t];
  re[l][t + 128] = inRe[base + t + 128];
  im[l][t + 128] = inIm[base + t + 128];
  fft256x2_lds(re, im, l, t, -1.f);
  float c0 = ctfT[base + t];
  float c1 = ctfT[base + t + 128];
  re[l][t] *= c0;
  im[l][t] *= c0;
  re[l][t + 128] *= c1;
  im[l][t + 128] *= c1;
  fft256x2_lds(re, im, l, t, 1.f);
  size_t ob = (size_t)b * kS * kS + (kx0 + l);
  outRe[ob + (size_t)t * kS] = re[l][t] * (1.f / 256.f);
  outIm[ob + (size_t)t * kS] = im[l][t] * (1.f / 256.f);
  outRe[ob + (size_t)(t + 128) * kS] = re[l][t + 128] * (1.f / 256.f);
  outIm[ob + (size_t)(t + 128) * kS] = im[l][t + 128] * (1.f / 256.f);
}

// Pass 3: inverse FFT over x, real part -> out image. 2 y-lines per block.
__global__ __launch_bounds__(256) void k_fft_rows_inv(
    const float* __restrict__ inRe, const float* __restrict__ inIm,
    float* __restrict__ out) {
  __shared__ float re[2][kS], im[2][kS];
  int tid = threadIdx.x;
  int blk = blockIdx.x;           // b*128 + y/2
  int b = blk >> 7, y0 = (blk & 127) * 2;
  int l = tid >> 7, t = tid & 127;
  size_t base = ((size_t)b * kS + y0 + l) * kS;
  re[l][t] = inRe[base + t];
  im[l][t] = inIm[base + t];
  re[l][t + 128] = inRe[base + t + 128];
  im[l][t + 128] = inIm[base + t + 128];
  fft256x2_lds(re, im, l, t, 1.f);
  out[base + t] = re[l][t] * (1.f / 256.f);
  out[base + t + 128] = re[l][t + 128] * (1.f / 256.f);
}

// ---------------------------------------------------------------------------
extern "C" void kernel_launch(void* const* d_in, const int* in_sizes, int n_in,
                              void* d_out, int out_size, void* d_ws,
                              size_t ws_size, hipStream_t stream) {
  const float* zx     = (const float*)d_in[0];
  const float* zy     = (const float*)d_in[1];
  const float* zz     = (const float*)d_in[2];
  const float* de     = (const float*)d_in[3];
  const float* dsh    = (const float*)d_in[4];
  const float* Zvol   = (const float*)d_in[5];
  const float* Za     = (const float*)d_in[6];
  const float* coords = (const float*)d_in[7];
  const float* values = (const float*)d_in[8];
  const float* ac     = (const float*)d_in[9];
  const float* ctf    = (const float*)d_in[10];
  const int*   bidx   = (const int*)d_in[11];
  const int*   aidx   = (const int*)d_in[12];

  float* ws    = (float*)d_ws;
  float* imgA  = ws;                           // scatter target; later dIm
  float* imgB  = ws + kImgElems;               // later dRe
  float* cRe   = ws + 2 * (size_t)kImgElems;
  float* cIm   = ws + 3 * (size_t)kImgElems;
  float* atoms = ws + 4 * (size_t)kImgElems;   // B*NA*3 floats
  unsigned* gcnt = (unsigned*)(atoms + (size_t)kB * kNA * 3);  // 256 counters
  float* proj = (float*)(gcnt + 256);          // kB*kProjStride floats
  uint2* arena = (uint2*)(proj + kB * kProjStride);
  size_t fixedBytes =
      (size_t)(4 * (size_t)kImgElems + (size_t)kB * kNA * 3 + 256 +
               kB * kProjStride) * 4;

  float* dRe = imgB;
  float* dIm = imgA;
  float* out_img   = (float*)d_out;
  float* out_bond  = out_img + kImgElems;
  float* out_angle = out_bond + (size_t)kB * kNB;
  // ctfT scratch lives in out_img: written by k_ctfT, read by k_fft_cols,
  // then overwritten by k_fft_rows_inv. Lifetimes do not overlap per-kernel.
  float* ctfT = out_img;

  size_t avail = (ws_size > fixedBytes) ? (ws_size - fixedBytes) : 0;
  bool full = ((size_t)kB * kNStrip * kCAP * sizeof(uint2)) <= avail;

  {
    dim3 tg(8, 8, kB);
    k_ctfT<<<tg, 256, 0, stream>>>(ctf, ctfT, zx, zy, zz, de, dsh, proj);
  }

  if (full) {
    hipMemsetAsync(gcnt, 0, 256 * sizeof(unsigned), stream);
    k_project<<<kProjBlocks + kAtomBlocks, kPB, 0, stream>>>(
        proj, Zvol, coords, values, arena, gcnt, zx, zy, zz, Za, ac, atoms);
    k_deposit_ba<<<kDepBlocks + kBABlocks, 1024, 0, stream>>>(
        arena, gcnt, imgA, atoms, bidx, aidx, out_bond, out_angle);
  } else {
    hipMemsetAsync(imgA, 0, (size_t)kImgElems * sizeof(float), stream);
    k_scatter<<<(kN + 255) / 256, 256, 0, stream>>>(proj, Zvol, coords, values,
                                                    imgA);
    k_atoms<<<(kNA + 255) / 256, 256, 0, stream>>>(zx, zy, zz, Za, ac, atoms);
    k_bondangle<<<(kBATotal + 255) / 256, 256, 0, stream>>>(
        atoms, bidx, aidx, out_bond, out_angle);
  }

  k_conv_fft_rows<<<kB * kS / 2, 256, 0, stream>>>(imgA, cRe, cIm);
  k_fft_cols<<<kB * kS / 2, 256, 0, stream>>>(cRe, cIm, ctfT, dRe, dIm);
  k_fft_rows_inv<<<kB * kS / 2, 256, 0, stream>>>(dRe, dIm, out_img);
}